// Round 2
// baseline (27502.261 us; speedup 1.0000x reference)
//
#include <hip/hip_runtime.h>
#include <hip/hip_cooperative_groups.h>

namespace cg = cooperative_groups;

// Problem constants (match reference)
#define IN_DIM 128
#define HID    512
#define BATCH  256
#define SEQT   512
#define G4H    2048      // 4*HID
#define K0     640       // IN_DIM + HID (layer0 fused input+recurrent GEMM)
#define K1     1024      // HID + HID   (layer1)
#define APAD   1032      // LDS row stride (shorts): 2064B = 516 dwords, 516%32=4 -> 2-way (free)

typedef __attribute__((ext_vector_type(8))) short bf16x8;
typedef __attribute__((ext_vector_type(4))) float f32x4;

__device__ __forceinline__ unsigned short f2bf(float f) {  // RNE float->bf16
  unsigned u = __float_as_uint(f);
  u += 0x7fffu + ((u >> 16) & 1u);
  return (unsigned short)(u >> 16);
}
__device__ __forceinline__ float bf2f(unsigned short s) {
  return __uint_as_float(((unsigned)s) << 16);
}
__device__ __forceinline__ float sigm(float x) {
  return 1.0f / (1.0f + __expf(-x));
}
__device__ __forceinline__ float tanh_f(float x) {
  float xc = fminf(fmaxf(x, -15.0f), 15.0f);   // clamp avoids inf/inf NaN
  float e = __expf(2.0f * xc);
  return (e - 1.0f) / (e + 1.0f);
}

// ---------------------------------------------------------------------------
// Weight pre-conversion: build concatenated [n][k] K-major hi/lo bf16 planes.
// Layer0: k<128 -> Wih0[n][k]; k>=128 -> Whh0[n][k-128]   (K0=640)
// Layer1: k<512 -> Wih1[n][k]; k>=512 -> Whh1[n][k-512]   (K1=1024)
// ---------------------------------------------------------------------------
__global__ void conv_weights(const float* __restrict__ Wih0, const float* __restrict__ Whh0,
                             const float* __restrict__ Wih1, const float* __restrict__ Whh1,
                             short* __restrict__ W0hi, short* __restrict__ W0lo,
                             short* __restrict__ W1hi, short* __restrict__ W1lo) {
  int idx = blockIdx.x * blockDim.x + threadIdx.x;
  const int N0 = G4H * K0;
  const int N1 = G4H * K1;
  if (idx < N0) {
    int n = idx / K0, k = idx % K0;
    float w = (k < IN_DIM) ? Wih0[n * IN_DIM + k] : Whh0[n * HID + (k - IN_DIM)];
    unsigned short hi = f2bf(w);
    W0hi[idx] = (short)hi;
    W0lo[idx] = (short)f2bf(w - bf2f(hi));
  } else if (idx < N0 + N1) {
    int j = idx - N0;
    int n = j / K1, k = j % K1;
    float w = (k < HID) ? Wih1[n * HID + k] : Whh1[n * HID + (k - HID)];
    unsigned short hi = f2bf(w);
    W1hi[j] = (short)hi;
    W1lo[j] = (short)f2bf(w - bf2f(hi));
  }
}

// ---------------------------------------------------------------------------
// Helpers for the persistent LSTM kernel
// ---------------------------------------------------------------------------
__device__ __forceinline__ void stage_h(short A[32][APAD], const short* __restrict__ plane,
                                        int b0, int off, int tid) {
  // Copy [32 rows x 512 shorts] from global h-plane into A[., off..off+512)
  const int r  = tid >> 3;            // 0..31
  const int j0 = (tid & 7) * 64;      // 8 threads per row, 64 shorts (128B) each
  const int4* src = (const int4*)(plane + (size_t)(b0 + r) * HID + j0);
  int4* dst = (int4*)(&A[r][off + j0]);
#pragma unroll
  for (int v = 0; v < 8; ++v) dst[v] = src[v];
}

__device__ __forceinline__ void gemm2(const short A_hi[32][APAD], const short A_lo[32][APAD],
                                      const short* __restrict__ Bhi, const short* __restrict__ Blo,
                                      int K, int lane, f32x4& acc0, f32x4& acc1) {
  // acc[m][n] += A[32,K] * W[n][k]^T for this wave's 16 columns.
  // Split precision: hi*hi + hi*lo + lo*hi (lo*lo negligible, ~2^-18 rel).
  const int row = lane & 15;
  const int ko  = (lane >> 4) * 8;
  const int nk  = K >> 5;
#pragma unroll 4
  for (int kc = 0; kc < nk; ++kc) {
    const int k = kc * 32 + ko;
    bf16x8 ah0 = *(const bf16x8*)&A_hi[row][k];
    bf16x8 ah1 = *(const bf16x8*)&A_hi[row + 16][k];
    bf16x8 al0 = *(const bf16x8*)&A_lo[row][k];
    bf16x8 al1 = *(const bf16x8*)&A_lo[row + 16][k];
    bf16x8 bh  = *(const bf16x8*)(Bhi + k);
    bf16x8 bl  = *(const bf16x8*)(Blo + k);
    acc0 = __builtin_amdgcn_mfma_f32_16x16x32_bf16(ah0, bh, acc0, 0, 0, 0);
    acc1 = __builtin_amdgcn_mfma_f32_16x16x32_bf16(ah1, bh, acc1, 0, 0, 0);
    acc0 = __builtin_amdgcn_mfma_f32_16x16x32_bf16(ah0, bl, acc0, 0, 0, 0);
    acc1 = __builtin_amdgcn_mfma_f32_16x16x32_bf16(ah1, bl, acc1, 0, 0, 0);
    acc0 = __builtin_amdgcn_mfma_f32_16x16x32_bf16(al0, bh, acc0, 0, 0, 0);
    acc1 = __builtin_amdgcn_mfma_f32_16x16x32_bf16(al1, bh, acc1, 0, 0, 0);
  }
}

__device__ __forceinline__ void fin(float gl[4][32][16], int wv, int lane,
                                    const f32x4& a0, const f32x4& a1) {
  // C/D layout: col = lane&15, row = (lane>>4)*4 + reg   [measured m89]
  const int col = lane & 15;
  const int r0  = (lane >> 4) * 4;
#pragma unroll
  for (int r = 0; r < 4; ++r) {
    gl[wv][r0 + r][col]      = a0[r];
    gl[wv][16 + r0 + r][col] = a1[r];
  }
}

__device__ __forceinline__ void update(float gl[4][32][16], float* c,
                                       const float* __restrict__ bih, const float* __restrict__ bhh,
                                       int hid0, int b0,
                                       short* __restrict__ hhi_p, short* __restrict__ hlo_p, int tid) {
#pragma unroll
  for (int j = 0; j < 2; ++j) {
    const int p  = tid * 2 + j;     // 0..511 -> (batch-row, hid-within-tile)
    const int r  = p >> 4;
    const int hl = p & 15;
    const int n  = hid0 + hl;
    float gi = gl[0][r][hl] + bih[n]           + bhh[n];
    float gf = gl[1][r][hl] + bih[HID + n]     + bhh[HID + n];
    float gg = gl[2][r][hl] + bih[2 * HID + n] + bhh[2 * HID + n];
    float go = gl[3][r][hl] + bih[3 * HID + n] + bhh[3 * HID + n];
    float i = sigm(gi), f = sigm(gf), g = tanh_f(gg), o = sigm(go);
    float cc = f * c[j] + i * g;
    c[j] = cc;
    float h = o * tanh_f(cc);
    unsigned short hh = f2bf(h);
    unsigned short hlo = f2bf(h - bf2f(hh));
    const size_t idx = (size_t)(b0 + r) * HID + n;
    hhi_p[idx] = (short)hh;
    hlo_p[idx] = (short)hlo;
  }
}

// ---------------------------------------------------------------------------
// Persistent fused 2-layer LSTM. Grid = 256 WGs x 256 thr (1 WG/CU).
// blockIdx%32 = hidden slice (same-slice WGs share XCD -> weight L2 reuse),
// blockIdx/32 = batch group of 32. Layer1 pipelined one step behind layer0.
// ---------------------------------------------------------------------------
__global__ void __launch_bounds__(256, 1) lstm_fused(
    const float* __restrict__ x,
    const float* __restrict__ bih0, const float* __restrict__ bhh0,
    const float* __restrict__ bih1, const float* __restrict__ bhh1,
    const float* __restrict__ Wfc, const float* __restrict__ bfc,
    const short* __restrict__ W0hi, const short* __restrict__ W0lo,
    const short* __restrict__ W1hi, const short* __restrict__ W1lo,
    short* __restrict__ h0s, short* __restrict__ h2s,
    float* __restrict__ out) {
  cg::grid_group grid = cg::this_grid();

  const int tid   = threadIdx.x;
  const int wv    = tid >> 6;          // wave = gate (i,f,g,o)
  const int lane  = tid & 63;
  const int slice = blockIdx.x & 31;
  const int grp   = blockIdx.x >> 5;
  const int hid0  = slice * 16;
  const int b0    = grp * 32;

  __shared__ short Ahi[32][APAD];      // activation hi plane [32, K<=1024]
  __shared__ short Alo[32][APAD];      // activation lo plane
  __shared__ float gl[4][32][16];      // gate exchange: [gate][batch][hid]

  float c0[2] = {0.f, 0.f};            // cell states live in registers all 512 steps
  float c1[2] = {0.f, 0.f};

  const int ncol = wv * HID + hid0 + (lane & 15);      // weight column for this lane
  const short* B0hi = W0hi + (size_t)ncol * K0;
  const short* B0lo = W0lo + (size_t)ncol * K0;
  const short* B1hi = W1hi + (size_t)ncol * K1;
  const short* B1lo = W1lo + (size_t)ncol * K1;

  const size_t PL = (size_t)BATCH * HID;               // plane stride

  for (int s = 0; s <= SEQT; ++s) {
    const int cur = s & 1;
    const int prv = cur ^ 1;
    short* h0c_hi = h0s + (size_t)(cur * 2 + 0) * PL;
    short* h0c_lo = h0s + (size_t)(cur * 2 + 1) * PL;
    const short* h0p_hi = h0s + (size_t)(prv * 2 + 0) * PL;
    const short* h0p_lo = h0s + (size_t)(prv * 2 + 1) * PL;
    short* h2c_hi = h2s + (size_t)(cur * 2 + 0) * PL;
    short* h2c_lo = h2s + (size_t)(cur * 2 + 1) * PL;
    const short* h2p_hi = h2s + (size_t)(prv * 2 + 0) * PL;
    const short* h2p_lo = h2s + (size_t)(prv * 2 + 1) * PL;

    if (s < SEQT) {  // -------- layer 0, time t = s --------
      {  // stage x_t -> A[., 0..128), converting fp32 -> hi/lo bf16
        const int r  = tid >> 3;
        const int i0 = (tid & 7) * 16;
        const float* xs = x + ((size_t)(b0 + r) * SEQT + s) * IN_DIM + i0;
#pragma unroll
        for (int v = 0; v < 16; ++v) {
          float f = xs[v];
          unsigned short hi = f2bf(f);
          Ahi[r][i0 + v] = (short)hi;
          Alo[r][i0 + v] = (short)f2bf(f - bf2f(hi));
        }
      }
      stage_h(Ahi, h0p_hi, b0, IN_DIM, tid);
      stage_h(Alo, h0p_lo, b0, IN_DIM, tid);
      __syncthreads();
      f32x4 a0 = {0.f, 0.f, 0.f, 0.f}, a1 = {0.f, 0.f, 0.f, 0.f};
      gemm2(Ahi, Alo, B0hi, B0lo, K0, lane, a0, a1);
      fin(gl, wv, lane, a0, a1);
      __syncthreads();
      update(gl, c0, bih0, bhh0, hid0, b0, h0c_hi, h0c_lo, tid);
    }
    if (s > 0) {     // -------- layer 1, time t = s-1 (pipelined) --------
      stage_h(Ahi, h0p_hi, b0, 0, tid);     // layer1 "x" input = h1_{t} = h0 prev buf
      stage_h(Alo, h0p_lo, b0, 0, tid);
      stage_h(Ahi, h2p_hi, b0, HID, tid);   // layer1 recurrent h
      stage_h(Alo, h2p_lo, b0, HID, tid);
      __syncthreads();                       // also orders update0's gl reads vs fin1's writes
      f32x4 a0 = {0.f, 0.f, 0.f, 0.f}, a1 = {0.f, 0.f, 0.f, 0.f};
      gemm2(Ahi, Alo, B1hi, B1lo, K1, lane, a0, a1);
      fin(gl, wv, lane, a0, a1);
      __syncthreads();
      update(gl, c1, bih1, bhh1, hid0, b0, h2c_hi, h2c_lo, tid);
    }
    grid.sync();   // device-wide: h buffers visible for next step
  }

  // -------- FC epilogue: out = h2[:,T-1,:] @ Wfc.T + bfc (h2 final in buf 0) --------
  if (blockIdx.x < 2) {
    const int e = blockIdx.x * 256 + tid;    // 0..511
    const int b = e >> 1, o = e & 1;
    const short* hhi = h2s + 0 * PL + (size_t)b * HID;
    const short* hlo = h2s + 1 * PL + (size_t)b * HID;
    const float* wf = Wfc + o * HID;
    float acc = 0.f;
    for (int k = 0; k < HID; ++k)
      acc += (bf2f((unsigned short)hhi[k]) + bf2f((unsigned short)hlo[k])) * wf[k];
    out[e] = acc + bfc[o];
  }
}

// ---------------------------------------------------------------------------
extern "C" void kernel_launch(void* const* d_in, const int* in_sizes, int n_in,
                              void* d_out, int out_size, void* d_ws, size_t ws_size,
                              hipStream_t stream) {
  const float* x    = (const float*)d_in[0];
  const float* Wih0 = (const float*)d_in[1];
  const float* Whh0 = (const float*)d_in[2];
  const float* bih0 = (const float*)d_in[3];
  const float* bhh0 = (const float*)d_in[4];
  const float* Wih1 = (const float*)d_in[5];
  const float* Whh1 = (const float*)d_in[6];
  const float* bih1 = (const float*)d_in[7];
  const float* bhh1 = (const float*)d_in[8];
  const float* Wfc  = (const float*)d_in[9];
  const float* bfc  = (const float*)d_in[10];
  float* out = (float*)d_out;

  // Workspace layout (shorts), total ~15.7 MB
  short* W0hi = (short*)d_ws;
  short* W0lo = W0hi + (size_t)G4H * K0;
  short* W1hi = W0lo + (size_t)G4H * K0;
  short* W1lo = W1hi + (size_t)G4H * K1;
  short* h0s  = W1lo + (size_t)G4H * K1;   // [2 buf][2 plane][BATCH][HID]
  short* h2s  = h0s + (size_t)4 * BATCH * HID;

  // Zero h state double-buffers (h0s..h2s contiguous: 8 planes)
  hipMemsetAsync(h0s, 0, (size_t)8 * BATCH * HID * sizeof(short), stream);

  const int totalW = G4H * K0 + G4H * K1;
  conv_weights<<<(totalW + 255) / 256, 256, 0, stream>>>(Wih0, Whh0, Wih1, Whh1,
                                                         W0hi, W0lo, W1hi, W1lo);

  void* args[] = {(void*)&x,    (void*)&bih0, (void*)&bhh0, (void*)&bih1, (void*)&bhh1,
                  (void*)&Wfc,  (void*)&bfc,
                  (void*)&W0hi, (void*)&W0lo, (void*)&W1hi, (void*)&W1lo,
                  (void*)&h0s,  (void*)&h2s,  (void*)&out};
  hipLaunchCooperativeKernel((void*)lstm_fused, dim3(256), dim3(256), args, 0, stream);
}

// Round 3
// 22973.125 us; speedup vs baseline: 1.1971x; 1.1971x over previous
//
#include <hip/hip_runtime.h>

// Problem constants
#define IN_DIM 128
#define HID    512
#define BATCH  256
#define SEQT   512
#define G4H    2048      // 4*HID
#define K0     640       // IN_DIM + HID (layer0 fused GEMM)
#define K1     1024      // HID + HID   (layer1 fused GEMM)
#define ACOLS  1152      // LDS A cols: x(128) | h0p(512) | h2p(512)
#define APAD   1160      // row stride shorts: 2320B = 580 dw; 580%32=4 -> optimal b128 banks

typedef __attribute__((ext_vector_type(8))) short bf16x8;
typedef __attribute__((ext_vector_type(4))) float f32x4;

__device__ __forceinline__ unsigned short f2bf(float f) {  // RNE float->bf16
  unsigned u = __float_as_uint(f);
  u += 0x7fffu + ((u >> 16) & 1u);
  return (unsigned short)(u >> 16);
}
__device__ __forceinline__ float bf2f(unsigned short s) {
  return __uint_as_float(((unsigned)s) << 16);
}
__device__ __forceinline__ float sigm(float x) { return 1.0f / (1.0f + __expf(-x)); }
__device__ __forceinline__ float tanh_f(float x) {
  float xc = fminf(fmaxf(x, -15.0f), 15.0f);
  float e = __expf(2.0f * xc);
  return (e - 1.0f) / (e + 1.0f);
}

// Coherent-at-MALL (agent scope) 4B accesses: correct regardless of XCD placement.
__device__ __forceinline__ unsigned ald(const unsigned* p) {
  return __hip_atomic_load(p, __ATOMIC_RELAXED, __HIP_MEMORY_SCOPE_AGENT);
}
__device__ __forceinline__ void ast(unsigned* p, unsigned v) {
  __hip_atomic_store(p, v, __ATOMIC_RELAXED, __HIP_MEMORY_SCOPE_AGENT);
}

// ---------------------------------------------------------------------------
// Prep: hi/lo bf16 weight planes (K-major concat) + bias sums.
// ---------------------------------------------------------------------------
__global__ void conv_weights(const float* __restrict__ Wih0, const float* __restrict__ Whh0,
                             const float* __restrict__ Wih1, const float* __restrict__ Whh1,
                             const float* __restrict__ bih0, const float* __restrict__ bhh0,
                             const float* __restrict__ bih1, const float* __restrict__ bhh1,
                             short* __restrict__ W0hi, short* __restrict__ W0lo,
                             short* __restrict__ W1hi, short* __restrict__ W1lo,
                             float* __restrict__ bsum0, float* __restrict__ bsum1) {
  int idx = blockIdx.x * blockDim.x + threadIdx.x;
  const int N0 = G4H * K0, N1 = G4H * K1;
  if (idx < N0) {
    int n = idx / K0, k = idx % K0;
    float w = (k < IN_DIM) ? Wih0[n * IN_DIM + k] : Whh0[n * HID + (k - IN_DIM)];
    unsigned short hi = f2bf(w);
    W0hi[idx] = (short)hi;
    W0lo[idx] = (short)f2bf(w - bf2f(hi));
  } else if (idx < N0 + N1) {
    int j = idx - N0;
    int n = j / K1, k = j % K1;
    float w = (k < HID) ? Wih1[n * HID + k] : Whh1[n * HID + (k - HID)];
    unsigned short hi = f2bf(w);
    W1hi[j] = (short)hi;
    W1lo[j] = (short)f2bf(w - bf2f(hi));
  } else if (idx < N0 + N1 + G4H) {
    int n = idx - (N0 + N1);
    bsum0[n] = bih0[n] + bhh0[n];
  } else if (idx < N0 + N1 + 2 * G4H) {
    int n = idx - (N0 + N1 + G4H);
    bsum1[n] = bih1[n] + bhh1[n];
  }
}

// ---------------------------------------------------------------------------
// Stage one h-plane [32 rows x 512 shorts] global->LDS via coherent dword loads,
// then b128 LDS writes (8 lanes/4-bank-group = optimal).
// ---------------------------------------------------------------------------
__device__ __forceinline__ void stage_plane(short (*A)[APAD], const short* __restrict__ plane,
                                            int b0, int colOff, int tid) {
  const int row = tid >> 3, chunk = tid & 7;   // 32 rows x 8 chunks of 128B
  const unsigned* src = (const unsigned*)(plane + (size_t)(b0 + row) * HID) + chunk * 32;
  unsigned v[32] __attribute__((aligned(16)));
#pragma unroll
  for (int i = 0; i < 32; ++i) v[i] = ald(src + i);
  int4* dst = (int4*)&A[row][colOff + chunk * 64];
#pragma unroll
  for (int c = 0; c < 8; ++c) dst[c] = ((const int4*)v)[c];
}

// ---------------------------------------------------------------------------
// 32xK x Kx16-per-wave GEMM, split-precision (hi*hi + hi*lo + lo*hi).
// ---------------------------------------------------------------------------
template <int NK>
__device__ __forceinline__ void gemm2(const short (*A_hi)[APAD], const short (*A_lo)[APAD],
                                      int aoff,
                                      const short* __restrict__ Bhi, const short* __restrict__ Blo,
                                      int lane, f32x4& acc0, f32x4& acc1) {
  const int row = lane & 15;
  const int ko  = (lane >> 4) * 8;
#pragma unroll 4
  for (int kc = 0; kc < NK; ++kc) {
    const int kb = kc * 32 + ko;
    const int k  = aoff + kb;
    bf16x8 ah0 = *(const bf16x8*)&A_hi[row][k];
    bf16x8 ah1 = *(const bf16x8*)&A_hi[row + 16][k];
    bf16x8 al0 = *(const bf16x8*)&A_lo[row][k];
    bf16x8 al1 = *(const bf16x8*)&A_lo[row + 16][k];
    bf16x8 bh  = *(const bf16x8*)(Bhi + kb);
    bf16x8 bl  = *(const bf16x8*)(Blo + kb);
    acc0 = __builtin_amdgcn_mfma_f32_16x16x32_bf16(ah0, bh, acc0, 0, 0, 0);
    acc1 = __builtin_amdgcn_mfma_f32_16x16x32_bf16(ah1, bh, acc1, 0, 0, 0);
    acc0 = __builtin_amdgcn_mfma_f32_16x16x32_bf16(ah0, bl, acc0, 0, 0, 0);
    acc1 = __builtin_amdgcn_mfma_f32_16x16x32_bf16(ah1, bl, acc1, 0, 0, 0);
    acc0 = __builtin_amdgcn_mfma_f32_16x16x32_bf16(al0, bh, acc0, 0, 0, 0);
    acc1 = __builtin_amdgcn_mfma_f32_16x16x32_bf16(al1, bh, acc1, 0, 0, 0);
  }
}

__device__ __forceinline__ void fin(float (*gl)[32][16], int wv, int lane,
                                    const f32x4& a0, const f32x4& a1) {
  // C/D layout: col = lane&15, row = (lane>>4)*4 + reg  [measured m89]
  const int col = lane & 15;
  const int r0  = (lane >> 4) * 4;
#pragma unroll
  for (int r = 0; r < 4; ++r) {
    gl[wv][r0 + r][col]      = a0[r];
    gl[wv][16 + r0 + r][col] = a1[r];
  }
}

__device__ __forceinline__ void do_update(const float (*gl)[32][16], float c[2],
                                          const float (*bs)[2], int b0, int hid0, int tid,
                                          short* __restrict__ hp_hi, short* __restrict__ hp_lo) {
  const int p0 = tid * 2, r = p0 >> 4, hl = p0 & 15;   // hl even
  unsigned hw = 0, lw = 0;
#pragma unroll
  for (int j = 0; j < 2; ++j) {
    float gi = gl[0][r][hl + j] + bs[0][j];
    float gf = gl[1][r][hl + j] + bs[1][j];
    float gg = gl[2][r][hl + j] + bs[2][j];
    float go = gl[3][r][hl + j] + bs[3][j];
    float i = sigm(gi), f = sigm(gf), g = tanh_f(gg), o = sigm(go);
    float cc = f * c[j] + i * g;
    c[j] = cc;
    float h = o * tanh_f(cc);
    unsigned short hh  = f2bf(h);
    unsigned short hlo = f2bf(h - bf2f(hh));
    hw |= ((unsigned)hh)  << (16 * j);
    lw |= ((unsigned)hlo) << (16 * j);
  }
  const size_t idx = (size_t)(b0 + r) * HID + hid0 + hl;   // even -> 4B aligned
  ast((unsigned*)(hp_hi + idx), hw);
  ast((unsigned*)(hp_lo + idx), lw);
}

// Per-group 32-WG barrier: monotone counter, relaxed agent atomics, no cache fences.
__device__ __forceinline__ void group_barrier(unsigned* cnt, unsigned target, int tid) {
  __syncthreads();                 // all waves' vmem drained (incl. h-stores) before arrival
  if (tid == 0) {
    asm volatile("s_waitcnt vmcnt(0)" ::: "memory");
    __hip_atomic_fetch_add(cnt, 1u, __ATOMIC_RELAXED, __HIP_MEMORY_SCOPE_AGENT);
    while (__hip_atomic_load(cnt, __ATOMIC_RELAXED, __HIP_MEMORY_SCOPE_AGENT) < target)
      __builtin_amdgcn_s_sleep(1);
  }
  __syncthreads();
}

// ---------------------------------------------------------------------------
// Persistent fused 2-layer LSTM. 256 WGs x 256 thr (1 WG/CU).
// slice = blk&31 (hidden slice; same-slice WGs land on same XCD under round-robin
// -> weight L2 reuse), grp = blk>>5 (batch group of 32; independent recurrences).
// Layer1 pipelined one step behind layer0. No grid.sync: per-group barriers.
// ---------------------------------------------------------------------------
__global__ void __launch_bounds__(256, 1) lstm_fused(
    const float* __restrict__ x,
    const float* __restrict__ Wfc, const float* __restrict__ bfc,
    const short* __restrict__ W0hi, const short* __restrict__ W0lo,
    const short* __restrict__ W1hi, const short* __restrict__ W1lo,
    const float* __restrict__ bsum0, const float* __restrict__ bsum1,
    short* __restrict__ h0s, short* __restrict__ h2s,
    unsigned* __restrict__ counters,
    float* __restrict__ out) {
  const int tid   = threadIdx.x;
  const int wv    = tid >> 6;          // wave = gate (i,f,g,o)
  const int lane  = tid & 63;
  const int slice = blockIdx.x & 31;
  const int grp   = blockIdx.x >> 5;
  const int hid0  = slice * 16;
  const int b0    = grp * 32;
  unsigned* cnt   = counters + grp * 64;          // 256B apart

  __shared__ short Ahi[32][APAD];      // [x | h0p | h2p] hi plane
  __shared__ short Alo[32][APAD];      // lo plane
  __shared__ float gl[4][32][16];      // gate exchange
  __shared__ float red[64][4];         // FC reduction

  float c0[2] = {0.f, 0.f}, c1[2] = {0.f, 0.f};

  // Per-thread bias registers (this thread's 2 hidden cols x 4 gates x 2 layers)
  float bs0[4][2], bs1[4][2];
  {
    const int n0 = hid0 + ((tid * 2) & 15);
#pragma unroll
    for (int g = 0; g < 4; ++g) {
      bs0[g][0] = bsum0[g * HID + n0];  bs0[g][1] = bsum0[g * HID + n0 + 1];
      bs1[g][0] = bsum1[g * HID + n0];  bs1[g][1] = bsum1[g * HID + n0 + 1];
    }
  }

  const int ncol = wv * HID + hid0 + (lane & 15);
  const short* B0hi = W0hi + (size_t)ncol * K0;
  const short* B0lo = W0lo + (size_t)ncol * K0;
  const short* B1hi = W1hi + (size_t)ncol * K1;
  const short* B1lo = W1lo + (size_t)ncol * K1;

  const size_t PL = (size_t)BATCH * HID;

  for (int s = 0; s <= SEQT; ++s) {
    const int cur = s & 1, prv = cur ^ 1;
    short* h0c_hi = h0s + (size_t)(cur * 2 + 0) * PL;
    short* h0c_lo = h0s + (size_t)(cur * 2 + 1) * PL;
    const short* h0p_hi = h0s + (size_t)(prv * 2 + 0) * PL;
    const short* h0p_lo = h0s + (size_t)(prv * 2 + 1) * PL;
    short* h2c_hi = h2s + (size_t)(cur * 2 + 0) * PL;
    short* h2c_lo = h2s + (size_t)(cur * 2 + 1) * PL;
    const short* h2p_hi = h2s + (size_t)(prv * 2 + 0) * PL;
    const short* h2p_lo = h2s + (size_t)(prv * 2 + 1) * PL;

    // ---- stage everything for this step ----
    if (s < SEQT) {  // x_t -> cols [0,128)
      const int row = tid >> 3, f0 = (tid & 7) * 16;
      const float* xs = x + ((size_t)(b0 + row) * SEQT + s) * IN_DIM + f0;
      float4 xv[4];
#pragma unroll
      for (int q = 0; q < 4; ++q) xv[q] = ((const float4*)xs)[q];
      unsigned hd[8] __attribute__((aligned(16)));
      unsigned ld[8] __attribute__((aligned(16)));
#pragma unroll
      for (int v = 0; v < 8; ++v) {
        float f0v = ((const float*)xv)[2 * v], f1v = ((const float*)xv)[2 * v + 1];
        unsigned short h0v = f2bf(f0v), h1v = f2bf(f1v);
        unsigned short l0v = f2bf(f0v - bf2f(h0v)), l1v = f2bf(f1v - bf2f(h1v));
        hd[v] = (unsigned)h0v | ((unsigned)h1v << 16);
        ld[v] = (unsigned)l0v | ((unsigned)l1v << 16);
      }
      ((int4*)&Ahi[row][f0])[0] = ((const int4*)hd)[0];
      ((int4*)&Ahi[row][f0])[1] = ((const int4*)hd)[1];
      ((int4*)&Alo[row][f0])[0] = ((const int4*)ld)[0];
      ((int4*)&Alo[row][f0])[1] = ((const int4*)ld)[1];
    }
    stage_plane(Ahi, h0p_hi, b0, IN_DIM, tid);   // h0p: shared by layer0-recur & layer1-input
    stage_plane(Alo, h0p_lo, b0, IN_DIM, tid);
    if (s > 0) {
      stage_plane(Ahi, h2p_hi, b0, IN_DIM + HID, tid);
      stage_plane(Alo, h2p_lo, b0, IN_DIM + HID, tid);
    }
    __syncthreads();

    if (s < SEQT) {  // ---- layer 0, time t=s ----
      f32x4 a0 = {0.f, 0.f, 0.f, 0.f}, a1 = {0.f, 0.f, 0.f, 0.f};
      gemm2<K0 / 32>(Ahi, Alo, 0, B0hi, B0lo, lane, a0, a1);
      fin(gl, wv, lane, a0, a1);
    }
    __syncthreads();
    if (s < SEQT) do_update(gl, c0, bs0, b0, hid0, tid, h0c_hi, h0c_lo);
    __syncthreads();   // gl reuse guard
    if (s > 0) {     // ---- layer 1, time t=s-1 ----
      f32x4 a0 = {0.f, 0.f, 0.f, 0.f}, a1 = {0.f, 0.f, 0.f, 0.f};
      gemm2<K1 / 32>(Ahi, Alo, IN_DIM, B1hi, B1lo, lane, a0, a1);
      fin(gl, wv, lane, a0, a1);
    }
    __syncthreads();
    if (s > 0) do_update(gl, c1, bs1, b0, hid0, tid, h2c_hi, h2c_lo);

    group_barrier(cnt, 32u * (unsigned)(s + 1), tid);
  }

  // ---- FC epilogue: per-group slice-0 WG handles its 32 rows (h2 final in buf 0) ----
  if (slice == 0) {
    const int p = tid >> 2, q = tid & 3;       // p: (row,out) pair 0..63; q: K quarter
    const int b = b0 + (p >> 1), o = p & 1;
    const unsigned* sh = (const unsigned*)(h2s + (size_t)b * HID) + q * 64;
    const unsigned* sl = (const unsigned*)(h2s + PL + (size_t)b * HID) + q * 64;
    const float* wf = Wfc + (size_t)o * HID + q * 128;
    float acc = 0.f;
#pragma unroll 8
    for (int i = 0; i < 64; ++i) {
      unsigned uh = ald(sh + i), ul = ald(sl + i);
      float v0 = bf2f((unsigned short)(uh & 0xffff)) + bf2f((unsigned short)(ul & 0xffff));
      float v1 = bf2f((unsigned short)(uh >> 16))    + bf2f((unsigned short)(ul >> 16));
      acc += v0 * wf[2 * i] + v1 * wf[2 * i + 1];
    }
    red[p][q] = acc;
    __syncthreads();
    if (q == 0) out[b * 2 + o] = red[p][0] + red[p][1] + red[p][2] + red[p][3] + bfc[o];
  }
}

// ---------------------------------------------------------------------------
extern "C" void kernel_launch(void* const* d_in, const int* in_sizes, int n_in,
                              void* d_out, int out_size, void* d_ws, size_t ws_size,
                              hipStream_t stream) {
  const float* x    = (const float*)d_in[0];
  const float* Wih0 = (const float*)d_in[1];
  const float* Whh0 = (const float*)d_in[2];
  const float* bih0 = (const float*)d_in[3];
  const float* bhh0 = (const float*)d_in[4];
  const float* Wih1 = (const float*)d_in[5];
  const float* Whh1 = (const float*)d_in[6];
  const float* bih1 = (const float*)d_in[7];
  const float* bhh1 = (const float*)d_in[8];
  const float* Wfc  = (const float*)d_in[9];
  const float* bfc  = (const float*)d_in[10];
  float* out = (float*)d_out;

  // Workspace layout (~15.75 MB)
  short* W0hi = (short*)d_ws;
  short* W0lo = W0hi + (size_t)G4H * K0;
  short* W1hi = W0lo + (size_t)G4H * K0;
  short* W1lo = W1hi + (size_t)G4H * K1;
  short* h0s  = W1lo + (size_t)G4H * K1;          // [2 buf][2 plane][BATCH][HID]
  short* h2s  = h0s + (size_t)4 * BATCH * HID;
  unsigned* counters = (unsigned*)(h2s + (size_t)4 * BATCH * HID);  // 8 groups x 64 dw
  float* bsum0 = (float*)(counters + 512);
  float* bsum1 = bsum0 + G4H;

  // Zero h double-buffers + barrier counters (must reset every launch for graph replay)
  hipMemsetAsync(h0s, 0, (size_t)8 * BATCH * HID * sizeof(short) + 512 * sizeof(unsigned),
                 stream);

  const int total = G4H * K0 + G4H * K1 + 2 * G4H;
  conv_weights<<<(total + 255) / 256, 256, 0, stream>>>(
      Wih0, Whh0, Wih1, Whh1, bih0, bhh0, bih1, bhh1,
      W0hi, W0lo, W1hi, W1lo, bsum0, bsum1);

  void* args[] = {(void*)&x,    (void*)&Wfc,  (void*)&bfc,
                  (void*)&W0hi, (void*)&W0lo, (void*)&W1hi, (void*)&W1lo,
                  (void*)&bsum0, (void*)&bsum1,
                  (void*)&h0s,  (void*)&h2s,  (void*)&counters, (void*)&out};
  hipLaunchCooperativeKernel((void*)lstm_fused, dim3(256), dim3(256), args, 0, stream);
}

// Round 4
// 21463.622 us; speedup vs baseline: 1.2813x; 1.0703x over previous
//
#include <hip/hip_runtime.h>

// Problem constants
#define IN_DIM 128
#define HID    512
#define BATCH  256
#define SEQT   512
#define G4H    2048
#define K0     640       // IN_DIM + HID (layer0 concat K)
#define K1     1024      // HID + HID   (layer1 concat K)
#define NC0    20        // K0/32 k-chunks
#define NC1    32        // K1/32
#define ACOLS  1152      // A-tile cols: x(128) | h0p(512) | h2p(512)
#define ROWB   2304      // bytes per A row = ACOLS*2 (= 18*128 -> rows 128B-aligned)

typedef __attribute__((ext_vector_type(8))) short bf16x8;
typedef __attribute__((ext_vector_type(4))) float f32x4;

#define MFMA16 __builtin_amdgcn_mfma_f32_16x16x32_bf16

__device__ __forceinline__ unsigned short f2bf(float f) {  // RNE float->bf16
  unsigned u = __float_as_uint(f);
  u += 0x7fffu + ((u >> 16) & 1u);
  return (unsigned short)(u >> 16);
}
__device__ __forceinline__ float bf2f(unsigned short s) {
  return __uint_as_float(((unsigned)s) << 16);
}
__device__ __forceinline__ float sigm(float x) { return 1.0f / (1.0f + __expf(-x)); }
__device__ __forceinline__ float tanh_f(float x) {
  float xc = fminf(fmaxf(x, -15.0f), 15.0f);
  float e = __expf(2.0f * xc);
  return (e - 1.0f) / (e + 1.0f);
}

// Agent-scope (MALL-coherent) accesses: correct across XCDs, bypass stale per-XCD L2.
__device__ __forceinline__ unsigned ald(const unsigned* p) {
  return __hip_atomic_load(p, __ATOMIC_RELAXED, __HIP_MEMORY_SCOPE_AGENT);
}
__device__ __forceinline__ void ast16(unsigned short* p, unsigned short v) {
  __hip_atomic_store(p, v, __ATOMIC_RELAXED, __HIP_MEMORY_SCOPE_AGENT);
}

// ---------------------------------------------------------------------------
// Prep: packed hi/lo bf16 weight tiles + bias sums.
// Packed layout: tile t = slice*4+gate; within tile: [kchunk][lane 0..63][8 shorts]
// where lane encodes (col = lane&15, ko = (lane>>4)*8) -> wave reads 1KB contiguous.
// ---------------------------------------------------------------------------
__global__ void conv_weights(const float* __restrict__ Wih0, const float* __restrict__ Whh0,
                             const float* __restrict__ Wih1, const float* __restrict__ Whh1,
                             const float* __restrict__ bih0, const float* __restrict__ bhh0,
                             const float* __restrict__ bih1, const float* __restrict__ bhh1,
                             short* __restrict__ W0h, short* __restrict__ W0l,
                             short* __restrict__ W1h, short* __restrict__ W1l,
                             float* __restrict__ bsum0, float* __restrict__ bsum1) {
  int idx = blockIdx.x * blockDim.x + threadIdx.x;
  const int N0 = G4H * K0, N1 = G4H * K1;
  if (idx < N0) {
    int tile = idx / (K0 * 16), rem = idx % (K0 * 16);
    int kcg = rem >> 9, l = (rem >> 3) & 63, j = rem & 7;
    int slice = tile >> 2, g = tile & 3;
    int c = l & 15, k = kcg * 32 + ((l >> 4) << 3) + j;
    int n = g * HID + slice * 16 + c;
    float w = (k < IN_DIM) ? Wih0[n * IN_DIM + k] : Whh0[n * HID + (k - IN_DIM)];
    unsigned short hi = f2bf(w);
    W0h[idx] = (short)hi;
    W0l[idx] = (short)f2bf(w - bf2f(hi));
  } else if (idx < N0 + N1) {
    int d = idx - N0;
    int tile = d / (K1 * 16), rem = d % (K1 * 16);
    int kcg = rem >> 9, l = (rem >> 3) & 63, j = rem & 7;
    int slice = tile >> 2, g = tile & 3;
    int c = l & 15, k = kcg * 32 + ((l >> 4) << 3) + j;
    int n = g * HID + slice * 16 + c;
    float w = (k < HID) ? Wih1[n * HID + k] : Whh1[n * HID + (k - HID)];
    unsigned short hi = f2bf(w);
    W1h[d] = (short)hi;
    W1l[d] = (short)f2bf(w - bf2f(hi));
  } else if (idx < N0 + N1 + G4H) {
    int n = idx - (N0 + N1);
    bsum0[n] = bih0[n] + bhh0[n];
  } else if (idx < N0 + N1 + 2 * G4H) {
    int n = idx - (N0 + N1 + G4H);
    bsum1[n] = bih1[n] + bhh1[n];
  }
}

// ---------------------------------------------------------------------------
// Stage one h-plane [32 x 512 shorts] -> swizzled LDS. 1024 thr: 32B each.
// ---------------------------------------------------------------------------
__device__ __forceinline__ void stage_plane(char* Abase, const short* __restrict__ plane,
                                            int b0, int colOff, int tid) {
  const int row = tid >> 5, t32 = tid & 31;
  const int rx = (row & 7) << 4;
  const unsigned* src = (const unsigned*)(plane + (size_t)(b0 + row) * HID) + t32 * 8;
  unsigned v[8];
#pragma unroll
  for (int i = 0; i < 8; ++i) v[i] = ald(src + i);
  const int byte0 = (colOff + t32 * 16) * 2;
  char* base = Abase + row * ROWB;
  int4 a = {(int)v[0], (int)v[1], (int)v[2], (int)v[3]};
  int4 b = {(int)v[4], (int)v[5], (int)v[6], (int)v[7]};
  *(int4*)(base + (byte0 ^ rx)) = a;
  *(int4*)(base + ((byte0 + 16) ^ rx)) = b;
}

// ---------------------------------------------------------------------------
// Per-wave GEMM over this wave's K-quarter: acc += A[32,*] x W[16 cols]^T.
// Split precision: hi*hi + hi*lo + lo*hi.
// ---------------------------------------------------------------------------
template <int NKC>
__device__ __forceinline__ void gemmq(const char* Ah, const char* Al,
                                      const short* __restrict__ Bh, const short* __restrict__ Bl,
                                      int lane, int aoff, f32x4& acc0, f32x4& acc1) {
  const int row = lane & 15;
  const int ko  = (lane >> 4) * 8;
  const int rx  = (row & 7) << 4;   // same for row and row+16
  const char* pAh0 = Ah + row * ROWB;
  const char* pAh1 = Ah + (row + 16) * ROWB;
  const char* pAl0 = Al + row * ROWB;
  const char* pAl1 = Al + (row + 16) * ROWB;
#pragma unroll
  for (int kc = 0; kc < NKC; ++kc) {
    const int off = ((aoff + kc * 32 + ko) * 2) ^ rx;
    bf16x8 ah0 = *(const bf16x8*)(pAh0 + off);
    bf16x8 ah1 = *(const bf16x8*)(pAh1 + off);
    bf16x8 al0 = *(const bf16x8*)(pAl0 + off);
    bf16x8 al1 = *(const bf16x8*)(pAl1 + off);
    bf16x8 bh  = *(const bf16x8*)(Bh + kc * 512 + lane * 8);
    bf16x8 bl  = *(const bf16x8*)(Bl + kc * 512 + lane * 8);
    acc0 = MFMA16(ah0, bh, acc0, 0, 0, 0);
    acc1 = MFMA16(ah1, bh, acc1, 0, 0, 0);
    acc0 = MFMA16(ah0, bl, acc0, 0, 0, 0);
    acc1 = MFMA16(ah1, bl, acc1, 0, 0, 0);
    acc0 = MFMA16(al0, bh, acc0, 0, 0, 0);
    acc1 = MFMA16(al1, bh, acc1, 0, 0, 0);
  }
}

__device__ __forceinline__ void finq(float* glf, int g, int lane,
                                     const f32x4& a0, const f32x4& a1) {
  // C/D layout: col = lane&15, row = (lane>>4)*4 + reg  [measured m89]
  const int col = lane & 15;
  const int r0  = (lane >> 4) * 4;
  float* base = glf + g * 512;
#pragma unroll
  for (int r = 0; r < 4; ++r) {
    atomicAdd(base + (r0 + r) * 16 + col, a0[r]);        // ds_add_f32
    atomicAdd(base + (16 + r0 + r) * 16 + col, a1[r]);
  }
}

// update (tid<512 only): read 4 gates, zero them (bijection), LSTM cell, store h.
__device__ __forceinline__ void do_update(float* glf, float& c, const float* bs,
                                          int b0, int hid0, int tid,
                                          short* __restrict__ hp_hi, short* __restrict__ hp_lo) {
  float gi = glf[tid]         + bs[0];
  float gf = glf[512 + tid]   + bs[1];
  float gg = glf[1024 + tid]  + bs[2];
  float go = glf[1536 + tid]  + bs[3];
  glf[tid] = 0.f; glf[512 + tid] = 0.f; glf[1024 + tid] = 0.f; glf[1536 + tid] = 0.f;
  float i = sigm(gi), f = sigm(gf), g = tanh_f(gg), o = sigm(go);
  float cc = f * c + i * g;
  c = cc;
  float h = o * tanh_f(cc);
  unsigned short hh  = f2bf(h);
  unsigned short hlo = f2bf(h - bf2f(hh));
  const size_t idx = (size_t)(b0 + (tid >> 4)) * HID + hid0 + (tid & 15);
  ast16((unsigned short*)hp_hi + idx, hh);
  ast16((unsigned short*)hp_lo + idx, hlo);
}

// Per-group 32-WG barrier: monotone counter, relaxed agent atomics, no cache fences.
__device__ __forceinline__ void group_barrier(unsigned* cnt, unsigned target, int tid) {
  __syncthreads();   // drains each wave's vmem (compiler emits s_waitcnt before s_barrier)
  if (tid == 0) {
    asm volatile("s_waitcnt vmcnt(0)" ::: "memory");
    __hip_atomic_fetch_add(cnt, 1u, __ATOMIC_RELAXED, __HIP_MEMORY_SCOPE_AGENT);
    while (__hip_atomic_load(cnt, __ATOMIC_RELAXED, __HIP_MEMORY_SCOPE_AGENT) < target)
      __builtin_amdgcn_s_sleep(1);
  }
  __syncthreads();
}

// ---------------------------------------------------------------------------
// Persistent fused 2-layer LSTM. 256 WGs x 1024 thr (16 waves = 4/SIMD).
// Wave w: gate g = w&3, K-quarter kq = w>>2; partial gate sums via LDS atomicAdd.
// slice = blk&31 (16 hidden cols), grp = blk>>5 (32 batch rows).
// Layer1 pipelined one step behind layer0.
// ---------------------------------------------------------------------------
__global__ void __launch_bounds__(1024, 4) lstm_fused(
    const float* __restrict__ x,
    const float* __restrict__ Wfc, const float* __restrict__ bfc,
    const short* __restrict__ W0h, const short* __restrict__ W0l,
    const short* __restrict__ W1h, const short* __restrict__ W1l,
    const float* __restrict__ bsum0, const float* __restrict__ bsum1,
    short* __restrict__ h0s, short* __restrict__ h2s,
    unsigned* __restrict__ counters,
    float* __restrict__ out) {
  const int tid   = threadIdx.x;
  const int wv    = tid >> 6;
  const int lane  = tid & 63;
  const int slice = blockIdx.x & 31;
  const int grp   = blockIdx.x >> 5;
  const int hid0  = slice * 16;
  const int b0    = grp * 32;
  unsigned* cnt   = counters + grp * 64;   // 256B apart

  __shared__ __align__(16) char AhiB[32 * ROWB];   // 73728 B
  __shared__ __align__(16) char AloB[32 * ROWB];   // 73728 B
  __shared__ float glf[4 * 512];                    // 8192 B (also FC scratch)

  const int g  = wv & 3;
  const int kq = wv >> 2;
  const short* B0hp = W0h + ((size_t)(slice * 4 + g) * NC0 + (size_t)kq * 5) * 512;
  const short* B0lp = W0l + ((size_t)(slice * 4 + g) * NC0 + (size_t)kq * 5) * 512;
  const short* B1hp = W1h + ((size_t)(slice * 4 + g) * NC1 + (size_t)kq * 8) * 512;
  const short* B1lp = W1l + ((size_t)(slice * 4 + g) * NC1 + (size_t)kq * 8) * 512;
  const int aoff0 = kq * 160;          // L0 A-offset (shorts)
  const int aoff1 = IN_DIM + kq * 256; // L1 A-offset

  float c0 = 0.f, c1 = 0.f;
  float bs0[4], bs1[4];
  if (tid < 512) {
    const int n = hid0 + (tid & 15);
#pragma unroll
    for (int q = 0; q < 4; ++q) { bs0[q] = bsum0[q * HID + n]; bs1[q] = bsum1[q * HID + n]; }
    // init gl to zero (fin uses atomicAdd)
    glf[tid] = 0.f; glf[512 + tid] = 0.f; glf[1024 + tid] = 0.f; glf[1536 + tid] = 0.f;
  }

  const size_t PL = (size_t)BATCH * HID;

  for (int s = 0; s <= SEQT; ++s) {
    const int cur = s & 1, prv = cur ^ 1;
    short* h0c_hi = h0s + (size_t)(cur * 2 + 0) * PL;
    short* h0c_lo = h0s + (size_t)(cur * 2 + 1) * PL;
    const short* h0p_hi = h0s + (size_t)(prv * 2 + 0) * PL;
    const short* h0p_lo = h0s + (size_t)(prv * 2 + 1) * PL;
    short* h2c_hi = h2s + (size_t)(cur * 2 + 0) * PL;
    short* h2c_lo = h2s + (size_t)(cur * 2 + 1) * PL;
    const short* h2p_hi = h2s + (size_t)(prv * 2 + 0) * PL;
    const short* h2p_lo = h2s + (size_t)(prv * 2 + 1) * PL;

    // ---- stage phase ----
    if (s < SEQT) {  // x_t -> cols [0,128) hi/lo
      const int row = tid >> 5, t32 = tid & 31;
      const int rx = (row & 7) << 4;
      const float* xs = x + ((size_t)(b0 + row) * SEQT + s) * IN_DIM + t32 * 4;
      float4 xv = *(const float4*)xs;
      unsigned short h0v = f2bf(xv.x), h1v = f2bf(xv.y), h2v = f2bf(xv.z), h3v = f2bf(xv.w);
      uint2 hd = {(unsigned)h0v | ((unsigned)h1v << 16), (unsigned)h2v | ((unsigned)h3v << 16)};
      uint2 ld = {(unsigned)f2bf(xv.x - bf2f(h0v)) | ((unsigned)f2bf(xv.y - bf2f(h1v)) << 16),
                  (unsigned)f2bf(xv.z - bf2f(h2v)) | ((unsigned)f2bf(xv.w - bf2f(h3v)) << 16)};
      const int byte = (t32 * 8) ^ rx;
      *(uint2*)(AhiB + row * ROWB + byte) = hd;
      *(uint2*)(AloB + row * ROWB + byte) = ld;
    }
    stage_plane(AhiB, h0p_hi, b0, IN_DIM, tid);   // h0p: L0 recurrent + L1 input
    stage_plane(AloB, h0p_lo, b0, IN_DIM, tid);
    if (s > 0) {
      stage_plane(AhiB, h2p_hi, b0, IN_DIM + HID, tid);
      stage_plane(AloB, h2p_lo, b0, IN_DIM + HID, tid);
    }
    __syncthreads();

    // ---- layer 0 (t = s) ----
    if (s < SEQT) {
      f32x4 a0 = {0.f, 0.f, 0.f, 0.f}, a1 = {0.f, 0.f, 0.f, 0.f};
      gemmq<5>(AhiB, AloB, B0hp, B0lp, lane, aoff0, a0, a1);
      finq(glf, g, lane, a0, a1);
    }
    __syncthreads();
    if (s < SEQT && tid < 512) do_update(glf, c0, bs0, b0, hid0, tid, h0c_hi, h0c_lo);
    __syncthreads();   // gl zeros visible before fin1 adds

    // ---- layer 1 (t = s-1) ----
    if (s > 0) {
      f32x4 a0 = {0.f, 0.f, 0.f, 0.f}, a1 = {0.f, 0.f, 0.f, 0.f};
      gemmq<8>(AhiB, AloB, B1hp, B1lp, lane, aoff1, a0, a1);
      finq(glf, g, lane, a0, a1);
    }
    __syncthreads();
    if (s > 0 && tid < 512) do_update(glf, c1, bs1, b0, hid0, tid, h2c_hi, h2c_lo);

    group_barrier(cnt, 32u * (unsigned)(s + 1), tid);
  }

  // ---- FC epilogue: slice-0 WG of each group does its 32 rows (h2 final buf 0) ----
  {
    const int p = tid >> 3, q = tid & 7;   // 64 (row,out) pairs x 8 K-eighths
    float acc = 0.f;
    if (slice == 0 && tid < 512) {
      const int b = b0 + (p >> 1), o = p & 1;
      const unsigned* sh = (const unsigned*)(h2s + (size_t)b * HID) + q * 32;
      const unsigned* sl = (const unsigned*)(h2s + PL + (size_t)b * HID) + q * 32;
      const float* wf = Wfc + (size_t)o * HID + q * 64;
#pragma unroll 8
      for (int i = 0; i < 32; ++i) {
        unsigned uh = ald(sh + i), ul = ald(sl + i);
        float v0 = bf2f((unsigned short)(uh & 0xffff)) + bf2f((unsigned short)(ul & 0xffff));
        float v1 = bf2f((unsigned short)(uh >> 16))    + bf2f((unsigned short)(ul >> 16));
        acc += v0 * wf[2 * i] + v1 * wf[2 * i + 1];
      }
      glf[p * 8 + q] = acc;
    }
    __syncthreads();
    if (slice == 0 && tid < 512 && q == 0) {
      float t = 0.f;
#pragma unroll
      for (int i = 0; i < 8; ++i) t += glf[p * 8 + i];
      out[(b0 + (p >> 1)) * 2 + (p & 1)] = t + bfc[p & 1];
    }
  }
}

// ---------------------------------------------------------------------------
extern "C" void kernel_launch(void* const* d_in, const int* in_sizes, int n_in,
                              void* d_out, int out_size, void* d_ws, size_t ws_size,
                              hipStream_t stream) {
  const float* x    = (const float*)d_in[0];
  const float* Wih0 = (const float*)d_in[1];
  const float* Whh0 = (const float*)d_in[2];
  const float* bih0 = (const float*)d_in[3];
  const float* bhh0 = (const float*)d_in[4];
  const float* Wih1 = (const float*)d_in[5];
  const float* Whh1 = (const float*)d_in[6];
  const float* bih1 = (const float*)d_in[7];
  const float* bhh1 = (const float*)d_in[8];
  const float* Wfc  = (const float*)d_in[9];
  const float* bfc  = (const float*)d_in[10];
  float* out = (float*)d_out;

  // Workspace layout (~15.8 MB)
  short* W0h = (short*)d_ws;
  short* W0l = W0h + (size_t)G4H * K0;
  short* W1h = W0l + (size_t)G4H * K0;
  short* W1l = W1h + (size_t)G4H * K1;
  short* h0s = W1l + (size_t)G4H * K1;            // [2 buf][2 plane][BATCH][HID]
  short* h2s = h0s + (size_t)4 * BATCH * HID;
  unsigned* counters = (unsigned*)(h2s + (size_t)4 * BATCH * HID);  // 8 x 64 dw
  float* bsum0 = (float*)(counters + 512);
  float* bsum1 = bsum0 + G4H;

  // Zero h double-buffers + barrier counters (reset every launch: graph-replay safe)
  hipMemsetAsync(h0s, 0, (size_t)8 * BATCH * HID * sizeof(short) + 512 * sizeof(unsigned),
                 stream);

  const int total = G4H * K0 + G4H * K1 + 2 * G4H;
  conv_weights<<<(total + 255) / 256, 256, 0, stream>>>(
      Wih0, Whh0, Wih1, Whh1, bih0, bhh0, bih1, bhh1,
      W0h, W0l, W1h, W1l, bsum0, bsum1);

  void* args[] = {(void*)&x,    (void*)&Wfc,  (void*)&bfc,
                  (void*)&W0h,  (void*)&W0l,  (void*)&W1h, (void*)&W1l,
                  (void*)&bsum0, (void*)&bsum1,
                  (void*)&h0s,  (void*)&h2s,  (void*)&counters, (void*)&out};
  hipLaunchCooperativeKernel((void*)lstm_fused, dim3(256), dim3(1024), args, 0, stream);
}

// Round 6
// 16845.236 us; speedup vs baseline: 1.6326x; 1.2742x over previous
//
#include <hip/hip_runtime.h>

// Problem constants
#define IN_DIM 128
#define HID    512
#define BATCH  256
#define SEQT   512
#define G4H    2048
#define K0     640       // IN_DIM + HID (layer0 concat K)
#define K1     1024      // HID + HID   (layer1 concat K)
#define NC0    20        // K0/32
#define NC1    32        // K1/32
#define ACOLS  1152      // A cols: x(128) | h0p(512) | h2p(512)
#define ROWB   2304      // bytes per A row (= 18*128, rows 128B-aligned)

typedef __attribute__((ext_vector_type(8))) short bf16x8;
typedef __attribute__((ext_vector_type(4))) float f32x4;

#define MFMA16 __builtin_amdgcn_mfma_f32_16x16x32_bf16

__device__ __forceinline__ unsigned short f2bf(float f) {  // RNE float->bf16
  unsigned u = __float_as_uint(f);
  u += 0x7fffu + ((u >> 16) & 1u);
  return (unsigned short)(u >> 16);
}
__device__ __forceinline__ float bf2f(unsigned short s) {
  return __uint_as_float(((unsigned)s) << 16);
}
__device__ __forceinline__ float sigm(float x) { return 1.0f / (1.0f + __expf(-x)); }
__device__ __forceinline__ float tanh_f(float x) {
  float xc = fminf(fmaxf(x, -15.0f), 15.0f);
  float e = __expf(2.0f * xc);
  return (e - 1.0f) / (e + 1.0f);
}

// dword agent-scope atomic load (barrier counter + FC reads)
__device__ __forceinline__ unsigned ald(const unsigned* p) {
  return __hip_atomic_load(p, __ATOMIC_RELAXED, __HIP_MEMORY_SCOPE_AGENT);
}

// ---------------------------------------------------------------------------
// Prep: packed hi/lo bf16 weight tiles + bias sums.
// Tile t = slice*4+gate; within tile: [kchunk][lane 0..63][8 shorts],
// lane = (col = lane&15, ko = (lane>>4)*8) -> wave reads 1KB contiguous.
// ---------------------------------------------------------------------------
__global__ void conv_weights(const float* __restrict__ Wih0, const float* __restrict__ Whh0,
                             const float* __restrict__ Wih1, const float* __restrict__ Whh1,
                             const float* __restrict__ bih0, const float* __restrict__ bhh0,
                             const float* __restrict__ bih1, const float* __restrict__ bhh1,
                             short* __restrict__ W0h, short* __restrict__ W0l,
                             short* __restrict__ W1h, short* __restrict__ W1l,
                             float* __restrict__ bsum0, float* __restrict__ bsum1) {
  int idx = blockIdx.x * blockDim.x + threadIdx.x;
  const int N0 = G4H * K0, N1 = G4H * K1;
  if (idx < N0) {
    int tile = idx / (K0 * 16), rem = idx % (K0 * 16);
    int kcg = rem >> 9, l = (rem >> 3) & 63, j = rem & 7;
    int slice = tile >> 2, g = tile & 3;
    int c = l & 15, k = kcg * 32 + ((l >> 4) << 3) + j;
    int n = g * HID + slice * 16 + c;
    float w = (k < IN_DIM) ? Wih0[n * IN_DIM + k] : Whh0[n * HID + (k - IN_DIM)];
    unsigned short hi = f2bf(w);
    W0h[idx] = (short)hi;
    W0l[idx] = (short)f2bf(w - bf2f(hi));
  } else if (idx < N0 + N1) {
    int d = idx - N0;
    int tile = d / (K1 * 16), rem = d % (K1 * 16);
    int kcg = rem >> 9, l = (rem >> 3) & 63, j = rem & 7;
    int slice = tile >> 2, g = tile & 3;
    int c = l & 15, k = kcg * 32 + ((l >> 4) << 3) + j;
    int n = g * HID + slice * 16 + c;
    float w = (k < HID) ? Wih1[n * HID + k] : Whh1[n * HID + (k - HID)];
    unsigned short hi = f2bf(w);
    W1h[d] = (short)hi;
    W1l[d] = (short)f2bf(w - bf2f(hi));
  } else if (idx < N0 + N1 + G4H) {
    int n = idx - (N0 + N1);
    bsum0[n] = bih0[n] + bhh0[n];
  } else if (idx < N0 + N1 + 2 * G4H) {
    int n = idx - (N0 + N1 + G4H);
    bsum1[n] = bih1[n] + bhh1[n];
  }
}

// ---------------------------------------------------------------------------
// Stage BOTH packed h planes (h0p, h2p) -> swizzled hi/lo LDS planes.
// Per thread: 64B from each plane via 8 batched device-coherent dwordx4 loads
// (ONE vmcnt for all 8 -> single latency window, 4x fewer MALL ops than dword).
// Packed element: dword = hi_bf16 | (lo_bf16 << 16).
// ---------------------------------------------------------------------------
__device__ __forceinline__ void stage_both(char* AhiB, char* AloB,
                                           const unsigned* __restrict__ h0p,
                                           const unsigned* __restrict__ h2p,
                                           int b0, int tid) {
  const int row = tid >> 5, c32 = tid & 31;          // 16 cols per thread per plane
  const unsigned* p0 = h0p + (size_t)(b0 + row) * HID + c32 * 16;
  const unsigned* p2 = h2p + (size_t)(b0 + row) * HID + c32 * 16;
  uint4 v0, v1, v2, v3, w0, w1, w2, w3;
  asm volatile(
      "global_load_dwordx4 %0, %8, off sc0 sc1\n\t"
      "global_load_dwordx4 %1, %8, off offset:16 sc0 sc1\n\t"
      "global_load_dwordx4 %2, %8, off offset:32 sc0 sc1\n\t"
      "global_load_dwordx4 %3, %8, off offset:48 sc0 sc1\n\t"
      "global_load_dwordx4 %4, %9, off sc0 sc1\n\t"
      "global_load_dwordx4 %5, %9, off offset:16 sc0 sc1\n\t"
      "global_load_dwordx4 %6, %9, off offset:32 sc0 sc1\n\t"
      "global_load_dwordx4 %7, %9, off offset:48 sc0 sc1\n\t"
      "s_waitcnt vmcnt(0)"
      : "=&v"(v0), "=&v"(v1), "=&v"(v2), "=&v"(v3),
        "=&v"(w0), "=&v"(w1), "=&v"(w2), "=&v"(w3)
      : "v"(p0), "v"(p2)
      : "memory");

  const int rx = (row & 7) << 4;
  char* bh = AhiB + row * ROWB;
  char* bl = AloB + row * ROWB;
#define PKH(a, b) ((unsigned)((a) & 0xffffu) | (((b) & 0xffffu) << 16))
#define PKL(a, b) (((a) >> 16) | ((b) & 0xffff0000u))
  // h0p -> cols [128, 640)
  {
    const int byte0 = (IN_DIM + c32 * 16) * 2;
    int4 h0 = {(int)PKH(v0.x, v0.y), (int)PKH(v0.z, v0.w), (int)PKH(v1.x, v1.y), (int)PKH(v1.z, v1.w)};
    int4 h1 = {(int)PKH(v2.x, v2.y), (int)PKH(v2.z, v2.w), (int)PKH(v3.x, v3.y), (int)PKH(v3.z, v3.w)};
    int4 l0 = {(int)PKL(v0.x, v0.y), (int)PKL(v0.z, v0.w), (int)PKL(v1.x, v1.y), (int)PKL(v1.z, v1.w)};
    int4 l1 = {(int)PKL(v2.x, v2.y), (int)PKL(v2.z, v2.w), (int)PKL(v3.x, v3.y), (int)PKL(v3.z, v3.w)};
    *(int4*)(bh + (byte0 ^ rx)) = h0;
    *(int4*)(bh + ((byte0 + 16) ^ rx)) = h1;
    *(int4*)(bl + (byte0 ^ rx)) = l0;
    *(int4*)(bl + ((byte0 + 16) ^ rx)) = l1;
  }
  // h2p -> cols [640, 1152)
  {
    const int byte0 = (IN_DIM + HID + c32 * 16) * 2;
    int4 h0 = {(int)PKH(w0.x, w0.y), (int)PKH(w0.z, w0.w), (int)PKH(w1.x, w1.y), (int)PKH(w1.z, w1.w)};
    int4 h1 = {(int)PKH(w2.x, w2.y), (int)PKH(w2.z, w2.w), (int)PKH(w3.x, w3.y), (int)PKH(w3.z, w3.w)};
    int4 l0 = {(int)PKL(w0.x, w0.y), (int)PKL(w0.z, w0.w), (int)PKL(w1.x, w1.y), (int)PKL(w1.z, w1.w)};
    int4 l1 = {(int)PKL(w2.x, w2.y), (int)PKL(w2.z, w2.w), (int)PKL(w3.x, w3.y), (int)PKL(w3.z, w3.w)};
    *(int4*)(bh + (byte0 ^ rx)) = h0;
    *(int4*)(bh + ((byte0 + 16) ^ rx)) = h1;
    *(int4*)(bl + (byte0 ^ rx)) = l0;
    *(int4*)(bl + ((byte0 + 16) ^ rx)) = l1;
  }
#undef PKH
#undef PKL
}

// ---------------------------------------------------------------------------
// Per-wave GEMM over this wave's K-quarter.
// ---------------------------------------------------------------------------
template <int NKC>
__device__ __forceinline__ void gemmq(const char* Ah, const char* Al,
                                      const short* __restrict__ Bh, const short* __restrict__ Bl,
                                      int lane, int aoff, f32x4& acc0, f32x4& acc1) {
  const int row = lane & 15;
  const int ko  = (lane >> 4) * 8;
  const int rx  = (row & 7) << 4;
  const char* pAh0 = Ah + row * ROWB;
  const char* pAh1 = Ah + (row + 16) * ROWB;
  const char* pAl0 = Al + row * ROWB;
  const char* pAl1 = Al + (row + 16) * ROWB;
#pragma unroll
  for (int kc = 0; kc < NKC; ++kc) {
    const int off = ((aoff + kc * 32 + ko) * 2) ^ rx;
    bf16x8 ah0 = *(const bf16x8*)(pAh0 + off);
    bf16x8 ah1 = *(const bf16x8*)(pAh1 + off);
    bf16x8 al0 = *(const bf16x8*)(pAl0 + off);
    bf16x8 al1 = *(const bf16x8*)(pAl1 + off);
    bf16x8 bh  = *(const bf16x8*)(Bh + kc * 512 + lane * 8);
    bf16x8 bl  = *(const bf16x8*)(Bl + kc * 512 + lane * 8);
    acc0 = MFMA16(ah0, bh, acc0, 0, 0, 0);
    acc1 = MFMA16(ah1, bh, acc1, 0, 0, 0);
    acc0 = MFMA16(ah0, bl, acc0, 0, 0, 0);
    acc1 = MFMA16(ah1, bl, acc1, 0, 0, 0);
    acc0 = MFMA16(al0, bh, acc0, 0, 0, 0);
    acc1 = MFMA16(al1, bh, acc1, 0, 0, 0);
  }
}

__device__ __forceinline__ void finq(float* glf, int g, int lane,
                                     const f32x4& a0, const f32x4& a1) {
  // C/D layout: col = lane&15, row = (lane>>4)*4 + reg  [measured m89]
  const int col = lane & 15;
  const int r0  = (lane >> 4) * 4;
  float* base = glf + g * 512;
#pragma unroll
  for (int r = 0; r < 4; ++r) {
    atomicAdd(base + (r0 + r) * 16 + col, a0[r]);        // ds_add_f32
    atomicAdd(base + (16 + r0 + r) * 16 + col, a1[r]);
  }
}

// update (tid<512): read 4 gates, zero them, LSTM cell, pack h -> LDS hbuf.
__device__ __forceinline__ void do_update(float* glf, float& c, const float* bs,
                                          int tid, unsigned (*hbuf)[16]) {
  float gi = glf[tid]        + bs[0];
  float gf = glf[512 + tid]  + bs[1];
  float gg = glf[1024 + tid] + bs[2];
  float go = glf[1536 + tid] + bs[3];
  glf[tid] = 0.f; glf[512 + tid] = 0.f; glf[1024 + tid] = 0.f; glf[1536 + tid] = 0.f;
  float i = sigm(gi), f = sigm(gf), g = tanh_f(gg), o = sigm(go);
  float cc = f * c + i * g;
  c = cc;
  float h = o * tanh_f(cc);
  unsigned short hh = f2bf(h);
  unsigned short hl = f2bf(h - bf2f(hh));
  hbuf[tid >> 4][tid & 15] = (unsigned)hh | ((unsigned)hl << 16);
}

// store phase: 128 threads write the 32x16 packed h tile as 2x u64 coherent stores.
__device__ __forceinline__ void store_h(const unsigned (*hbuf)[16], unsigned* hc,
                                        int b0, int hid0, int tid) {
  if (tid < 128) {
    const int row = tid >> 2, q = tid & 3;
    const unsigned long long* src = (const unsigned long long*)&hbuf[row][q * 4];
    unsigned long long* dst =
        (unsigned long long*)(hc + (size_t)(b0 + row) * HID + hid0 + q * 4);
    __hip_atomic_store(dst, src[0], __ATOMIC_RELAXED, __HIP_MEMORY_SCOPE_AGENT);
    __hip_atomic_store(dst + 1, src[1], __ATOMIC_RELAXED, __HIP_MEMORY_SCOPE_AGENT);
  }
}

// Per-group 32-WG barrier: drain vmem, syncthreads, tid0 counter round-trip.
__device__ __forceinline__ void group_barrier(unsigned* cnt, unsigned target, int tid) {
  asm volatile("s_waitcnt vmcnt(0)" ::: "memory");
  __syncthreads();
  if (tid == 0) {
    __hip_atomic_fetch_add(cnt, 1u, __ATOMIC_RELAXED, __HIP_MEMORY_SCOPE_AGENT);
    while (__hip_atomic_load(cnt, __ATOMIC_RELAXED, __HIP_MEMORY_SCOPE_AGENT) < target)
      __builtin_amdgcn_s_sleep(1);
  }
  __syncthreads();
}

// ---------------------------------------------------------------------------
// Persistent fused 2-layer LSTM. 256 WGs x 1024 thr (16 waves, 4/SIMD).
// Wave w: gate g = w&3, K-quarter kq = w>>2; gate partials via LDS atomicAdd.
// slice = blk&31 (16 hidden cols), grp = blk>>5 (32 batch rows).
// h exchanged as packed (hi|lo<<16) dwords via wide device-coherent accesses.
// ---------------------------------------------------------------------------
__global__ void __launch_bounds__(1024, 4) lstm_fused(
    const float* __restrict__ x,
    const float* __restrict__ Wfc, const float* __restrict__ bfc,
    const short* __restrict__ W0h, const short* __restrict__ W0l,
    const short* __restrict__ W1h, const short* __restrict__ W1l,
    const float* __restrict__ bsum0, const float* __restrict__ bsum1,
    unsigned* __restrict__ h0s, unsigned* __restrict__ h2s,
    unsigned* __restrict__ counters,
    float* __restrict__ out) {
  const int tid   = threadIdx.x;
  const int wv    = tid >> 6;
  const int lane  = tid & 63;
  const int slice = blockIdx.x & 31;
  const int grp   = blockIdx.x >> 5;
  const int hid0  = slice * 16;
  const int b0    = grp * 32;
  unsigned* cnt   = counters + grp * 64;

  __shared__ __align__(16) char AhiB[32 * ROWB];      // 73728 B
  __shared__ __align__(16) char AloB[32 * ROWB];      // 73728 B
  __shared__ float glf[4 * 512];                       // 8192 B (also FC scratch)
  __shared__ __align__(16) unsigned hbuf[32][16];      // 2048 B packed-h repack

  const int g  = wv & 3;
  const int kq = wv >> 2;
  const short* B0hp = W0h + ((size_t)(slice * 4 + g) * NC0 + (size_t)kq * 5) * 512;
  const short* B0lp = W0l + ((size_t)(slice * 4 + g) * NC0 + (size_t)kq * 5) * 512;
  const short* B1hp = W1h + ((size_t)(slice * 4 + g) * NC1 + (size_t)kq * 8) * 512;
  const short* B1lp = W1l + ((size_t)(slice * 4 + g) * NC1 + (size_t)kq * 8) * 512;
  const int aoff0 = kq * 160;
  const int aoff1 = IN_DIM + kq * 256;

  float c0 = 0.f, c1 = 0.f;
  float bs0[4], bs1[4];
  if (tid < 512) {
    const int n = hid0 + (tid & 15);
#pragma unroll
    for (int q = 0; q < 4; ++q) { bs0[q] = bsum0[q * HID + n]; bs1[q] = bsum1[q * HID + n]; }
    glf[tid] = 0.f; glf[512 + tid] = 0.f; glf[1024 + tid] = 0.f; glf[1536 + tid] = 0.f;
  }

  const size_t PL = (size_t)BATCH * HID;

  for (int s = 0; s <= SEQT; ++s) {
    const int cur = s & 1, prv = cur ^ 1;
    unsigned* h0c = h0s + (size_t)cur * PL;
    const unsigned* h0p = h0s + (size_t)prv * PL;
    unsigned* h2c = h2s + (size_t)cur * PL;
    const unsigned* h2p = h2s + (size_t)prv * PL;

    // ---- stage phase ----
    if (s < SEQT) {  // x_t -> cols [0,128) hi/lo (plain cached loads)
      const int row = tid >> 5, t32 = tid & 31;
      const int rx = (row & 7) << 4;
      const float* xs = x + ((size_t)(b0 + row) * SEQT + s) * IN_DIM + t32 * 4;
      float4 xv = *(const float4*)xs;
      unsigned short h0v = f2bf(xv.x), h1v = f2bf(xv.y), h2v = f2bf(xv.z), h3v = f2bf(xv.w);
      uint2 hd = {(unsigned)h0v | ((unsigned)h1v << 16), (unsigned)h2v | ((unsigned)h3v << 16)};
      uint2 ld = {(unsigned)f2bf(xv.x - bf2f(h0v)) | ((unsigned)f2bf(xv.y - bf2f(h1v)) << 16),
                  (unsigned)f2bf(xv.z - bf2f(h2v)) | ((unsigned)f2bf(xv.w - bf2f(h3v)) << 16)};
      const int byte = (t32 * 8) ^ rx;
      *(uint2*)(AhiB + row * ROWB + byte) = hd;
      *(uint2*)(AloB + row * ROWB + byte) = ld;
    }
    stage_both(AhiB, AloB, h0p, h2p, b0, tid);   // h2p region garbage at s=0 (unused)
    __syncthreads();

    // ---- layer 0 (t = s) ----
    if (s < SEQT) {
      f32x4 a0 = {0.f, 0.f, 0.f, 0.f}, a1 = {0.f, 0.f, 0.f, 0.f};
      gemmq<5>(AhiB, AloB, B0hp, B0lp, lane, aoff0, a0, a1);
      finq(glf, g, lane, a0, a1);
    }
    __syncthreads();
    if (s < SEQT && tid < 512) do_update(glf, c0, bs0, tid, hbuf);
    __syncthreads();   // hbuf + gl zeros visible

    // ---- store h0, overlapped with layer 1 (t = s-1) ----
    if (s < SEQT) store_h(hbuf, h0c, b0, hid0, tid);
    if (s > 0) {
      f32x4 a0 = {0.f, 0.f, 0.f, 0.f}, a1 = {0.f, 0.f, 0.f, 0.f};
      gemmq<8>(AhiB, AloB, B1hp, B1lp, lane, aoff1, a0, a1);
      finq(glf, g, lane, a0, a1);
    }
    __syncthreads();
    if (s > 0 && tid < 512) do_update(glf, c1, bs1, tid, hbuf);
    __syncthreads();   // hbuf visible
    if (s > 0) store_h(hbuf, h2c, b0, hid0, tid);

    group_barrier(cnt, 32u * (unsigned)(s + 1), tid);
  }

  // ---- FC epilogue: slice-0 WG of each group (h2 final in buf 0) ----
  {
    const int p = tid >> 3, q = tid & 7;   // 64 (row,out) pairs x 8 K-eighths
    float acc = 0.f;
    if (slice == 0 && tid < 512) {
      const int b = b0 + (p >> 1), o = p & 1;
      const unsigned* sp = h2s + (size_t)b * HID + q * 64;
      const float* wf = Wfc + (size_t)o * HID + q * 64;
#pragma unroll 8
      for (int i = 0; i < 64; ++i) {
        unsigned u = ald(sp + i);
        acc += (bf2f((unsigned short)(u & 0xffff)) + bf2f((unsigned short)(u >> 16))) * wf[i];
      }
      glf[p * 8 + q] = acc;
    }
    __syncthreads();
    if (slice == 0 && tid < 512 && q == 0) {
      float t = 0.f;
#pragma unroll
      for (int i = 0; i < 8; ++i) t += glf[p * 8 + i];
      out[(b0 + (p >> 1)) * 2 + (p & 1)] = t + bfc[p & 1];
    }
  }
}

// ---------------------------------------------------------------------------
extern "C" void kernel_launch(void* const* d_in, const int* in_sizes, int n_in,
                              void* d_out, int out_size, void* d_ws, size_t ws_size,
                              hipStream_t stream) {
  const float* x    = (const float*)d_in[0];
  const float* Wih0 = (const float*)d_in[1];
  const float* Whh0 = (const float*)d_in[2];
  const float* bih0 = (const float*)d_in[3];
  const float* bhh0 = (const float*)d_in[4];
  const float* Wih1 = (const float*)d_in[5];
  const float* Whh1 = (const float*)d_in[6];
  const float* bih1 = (const float*)d_in[7];
  const float* bhh1 = (const float*)d_in[8];
  const float* Wfc  = (const float*)d_in[9];
  const float* bfc  = (const float*)d_in[10];
  float* out = (float*)d_out;

  // Workspace layout (~15.7 MB)
  short* W0h = (short*)d_ws;
  short* W0l = W0h + (size_t)G4H * K0;
  short* W1h = W0l + (size_t)G4H * K0;
  short* W1l = W1h + (size_t)G4H * K1;
  unsigned* h0s = (unsigned*)(W1l + (size_t)G4H * K1);   // [2 buf][BATCH][HID] packed
  unsigned* h2s = h0s + (size_t)2 * BATCH * HID;
  unsigned* counters = h2s + (size_t)2 * BATCH * HID;     // 8 x 64 dw
  float* bsum0 = (float*)(counters + 512);
  float* bsum1 = bsum0 + G4H;

  // Zero h double-buffers + counters (every launch: graph-replay safe)
  (void)hipMemsetAsync(h0s, 0,
                       (size_t)4 * BATCH * HID * sizeof(unsigned) + 512 * sizeof(unsigned),
                       stream);

  const int total = G4H * K0 + G4H * K1 + 2 * G4H;
  conv_weights<<<(total + 255) / 256, 256, 0, stream>>>(
      Wih0, Whh0, Wih1, Whh1, bih0, bhh0, bih1, bhh1,
      W0h, W0l, W1h, W1l, bsum0, bsum1);

  void* args[] = {(void*)&x,    (void*)&Wfc,  (void*)&bfc,
                  (void*)&W0h,  (void*)&W0l,  (void*)&W1h, (void*)&W1l,
                  (void*)&bsum0, (void*)&bsum1,
                  (void*)&h0s,  (void*)&h2s,  (void*)&counters, (void*)&out};
  (void)hipLaunchCooperativeKernel((void*)lstm_fused, dim3(256), dim3(1024), args, 0,
                                   stream);
}

// Round 7
// 16739.494 us; speedup vs baseline: 1.6430x; 1.0063x over previous
//
#include <hip/hip_runtime.h>

// Problem constants
#define IN_DIM 128
#define HID    512
#define BATCH  256
#define SEQT   512
#define G4H    2048
#define K0     640       // IN_DIM + HID (layer0 concat K)
#define K1     1024      // HID + HID   (layer1 concat K)
#define NC0    20        // K0/32
#define NC1    32        // K1/32
#define ACOLS  1152      // A cols: x(128) | h0p(512) | h2p(512)
#define ROWB   2304      // bytes per A row (= 18*128, rows 128B-aligned)

typedef __attribute__((ext_vector_type(8))) short bf16x8;
typedef __attribute__((ext_vector_type(4))) float f32x4;

#define MFMA16 __builtin_amdgcn_mfma_f32_16x16x32_bf16

__device__ __forceinline__ unsigned short f2bf(float f) {  // RNE float->bf16
  unsigned u = __float_as_uint(f);
  u += 0x7fffu + ((u >> 16) & 1u);
  return (unsigned short)(u >> 16);
}
__device__ __forceinline__ float bf2f(unsigned short s) {
  return __uint_as_float(((unsigned)s) << 16);
}
__device__ __forceinline__ float sigm(float x) { return 1.0f / (1.0f + __expf(-x)); }
__device__ __forceinline__ float tanh_f(float x) {
  float xc = fminf(fmaxf(x, -15.0f), 15.0f);
  float e = __expf(2.0f * xc);
  return (e - 1.0f) / (e + 1.0f);
}

// dword agent-scope atomic load (barrier counter + FC reads)
__device__ __forceinline__ unsigned ald(const unsigned* p) {
  return __hip_atomic_load(p, __ATOMIC_RELAXED, __HIP_MEMORY_SCOPE_AGENT);
}

// ---------------------------------------------------------------------------
// Prep: packed hi/lo bf16 weight tiles + bias sums.
// Tile t = slice*4+gate; within tile: [kchunk][lane 0..63][8 shorts],
// lane = (col = lane&15, ko = (lane>>4)*8) -> wave reads 1KB contiguous.
// ---------------------------------------------------------------------------
__global__ void conv_weights(const float* __restrict__ Wih0, const float* __restrict__ Whh0,
                             const float* __restrict__ Wih1, const float* __restrict__ Whh1,
                             const float* __restrict__ bih0, const float* __restrict__ bhh0,
                             const float* __restrict__ bih1, const float* __restrict__ bhh1,
                             short* __restrict__ W0h, short* __restrict__ W0l,
                             short* __restrict__ W1h, short* __restrict__ W1l,
                             float* __restrict__ bsum0, float* __restrict__ bsum1) {
  int idx = blockIdx.x * blockDim.x + threadIdx.x;
  const int N0 = G4H * K0, N1 = G4H * K1;
  if (idx < N0) {
    int tile = idx / (K0 * 16), rem = idx % (K0 * 16);
    int kcg = rem >> 9, l = (rem >> 3) & 63, j = rem & 7;
    int slice = tile >> 2, g = tile & 3;
    int c = l & 15, k = kcg * 32 + ((l >> 4) << 3) + j;
    int n = g * HID + slice * 16 + c;
    float w = (k < IN_DIM) ? Wih0[n * IN_DIM + k] : Whh0[n * HID + (k - IN_DIM)];
    unsigned short hi = f2bf(w);
    W0h[idx] = (short)hi;
    W0l[idx] = (short)f2bf(w - bf2f(hi));
  } else if (idx < N0 + N1) {
    int d = idx - N0;
    int tile = d / (K1 * 16), rem = d % (K1 * 16);
    int kcg = rem >> 9, l = (rem >> 3) & 63, j = rem & 7;
    int slice = tile >> 2, g = tile & 3;
    int c = l & 15, k = kcg * 32 + ((l >> 4) << 3) + j;
    int n = g * HID + slice * 16 + c;
    float w = (k < HID) ? Wih1[n * HID + k] : Whh1[n * HID + (k - HID)];
    unsigned short hi = f2bf(w);
    W1h[d] = (short)hi;
    W1l[d] = (short)f2bf(w - bf2f(hi));
  } else if (idx < N0 + N1 + G4H) {
    int n = idx - (N0 + N1);
    bsum0[n] = bih0[n] + bhh0[n];
  } else if (idx < N0 + N1 + 2 * G4H) {
    int n = idx - (N0 + N1 + G4H);
    bsum1[n] = bih1[n] + bhh1[n];
  }
}

// ---------------------------------------------------------------------------
// Stage BOTH packed h planes (h0p, h2p) -> swizzled hi/lo LDS planes.
// Per thread: 64B from each plane via 8 batched device-coherent dwordx4 loads.
// Packed element: dword = hi_bf16 | (lo_bf16 << 16).
// ---------------------------------------------------------------------------
__device__ __forceinline__ void stage_both(char* AhiB, char* AloB,
                                           const unsigned* __restrict__ h0p,
                                           const unsigned* __restrict__ h2p,
                                           int b0, int tid) {
  const int row = tid >> 5, c32 = tid & 31;          // 16 cols per thread per plane
  const unsigned* p0 = h0p + (size_t)(b0 + row) * HID + c32 * 16;
  const unsigned* p2 = h2p + (size_t)(b0 + row) * HID + c32 * 16;
  uint4 v0, v1, v2, v3, w0, w1, w2, w3;
  asm volatile(
      "global_load_dwordx4 %0, %8, off sc0 sc1\n\t"
      "global_load_dwordx4 %1, %8, off offset:16 sc0 sc1\n\t"
      "global_load_dwordx4 %2, %8, off offset:32 sc0 sc1\n\t"
      "global_load_dwordx4 %3, %8, off offset:48 sc0 sc1\n\t"
      "global_load_dwordx4 %4, %9, off sc0 sc1\n\t"
      "global_load_dwordx4 %5, %9, off offset:16 sc0 sc1\n\t"
      "global_load_dwordx4 %6, %9, off offset:32 sc0 sc1\n\t"
      "global_load_dwordx4 %7, %9, off offset:48 sc0 sc1\n\t"
      "s_waitcnt vmcnt(0)"
      : "=&v"(v0), "=&v"(v1), "=&v"(v2), "=&v"(v3),
        "=&v"(w0), "=&v"(w1), "=&v"(w2), "=&v"(w3)
      : "v"(p0), "v"(p2)
      : "memory");

  const int rx = (row & 7) << 4;
  char* bh = AhiB + row * ROWB;
  char* bl = AloB + row * ROWB;
#define PKH(a, b) ((unsigned)((a) & 0xffffu) | (((b) & 0xffffu) << 16))
#define PKL(a, b) (((a) >> 16) | ((b) & 0xffff0000u))
  // h0p -> cols [128, 640)
  {
    const int byte0 = (IN_DIM + c32 * 16) * 2;
    int4 h0 = {(int)PKH(v0.x, v0.y), (int)PKH(v0.z, v0.w), (int)PKH(v1.x, v1.y), (int)PKH(v1.z, v1.w)};
    int4 h1 = {(int)PKH(v2.x, v2.y), (int)PKH(v2.z, v2.w), (int)PKH(v3.x, v3.y), (int)PKH(v3.z, v3.w)};
    int4 l0 = {(int)PKL(v0.x, v0.y), (int)PKL(v0.z, v0.w), (int)PKL(v1.x, v1.y), (int)PKL(v1.z, v1.w)};
    int4 l1 = {(int)PKL(v2.x, v2.y), (int)PKL(v2.z, v2.w), (int)PKL(v3.x, v3.y), (int)PKL(v3.z, v3.w)};
    *(int4*)(bh + (byte0 ^ rx)) = h0;
    *(int4*)(bh + ((byte0 + 16) ^ rx)) = h1;
    *(int4*)(bl + (byte0 ^ rx)) = l0;
    *(int4*)(bl + ((byte0 + 16) ^ rx)) = l1;
  }
  // h2p -> cols [640, 1152)
  {
    const int byte0 = (IN_DIM + HID + c32 * 16) * 2;
    int4 h0 = {(int)PKH(w0.x, w0.y), (int)PKH(w0.z, w0.w), (int)PKH(w1.x, w1.y), (int)PKH(w1.z, w1.w)};
    int4 h1 = {(int)PKH(w2.x, w2.y), (int)PKH(w2.z, w2.w), (int)PKH(w3.x, w3.y), (int)PKH(w3.z, w3.w)};
    int4 l0 = {(int)PKL(w0.x, w0.y), (int)PKL(w0.z, w0.w), (int)PKL(w1.x, w1.y), (int)PKL(w1.z, w1.w)};
    int4 l1 = {(int)PKL(w2.x, w2.y), (int)PKL(w2.z, w2.w), (int)PKL(w3.x, w3.y), (int)PKL(w3.z, w3.w)};
    *(int4*)(bh + (byte0 ^ rx)) = h0;
    *(int4*)(bh + ((byte0 + 16) ^ rx)) = h1;
    *(int4*)(bl + (byte0 ^ rx)) = l0;
    *(int4*)(bl + ((byte0 + 16) ^ rx)) = l1;
  }
#undef PKH
#undef PKL
}

// ---------------------------------------------------------------------------
// Per-wave GEMM over NKC k-chunks with FULL static B-prefetch: all 2*NKC
// B-tile loads issue back-to-back (one latency window), then LDS+MFMA.
// Keep NKC <= 4 so B regs (2*NKC*8) stay <= 64 (4-wave/SIMD VGPR budget 128).
// ---------------------------------------------------------------------------
template <int NKC>
__device__ __forceinline__ void gemmq(const char* Ah, const char* Al,
                                      const short* __restrict__ Bh, const short* __restrict__ Bl,
                                      int lane, int aoff, f32x4& acc0, f32x4& acc1) {
  const int row = lane & 15;
  const int ko  = (lane >> 4) * 8;
  const int rx  = (row & 7) << 4;
  bf16x8 bhp[NKC], blp[NKC];
#pragma unroll
  for (int kc = 0; kc < NKC; ++kc) {
    bhp[kc] = *(const bf16x8*)(Bh + kc * 512 + lane * 8);
    blp[kc] = *(const bf16x8*)(Bl + kc * 512 + lane * 8);
  }
  const char* pAh0 = Ah + row * ROWB;
  const char* pAh1 = Ah + (row + 16) * ROWB;
  const char* pAl0 = Al + row * ROWB;
  const char* pAl1 = Al + (row + 16) * ROWB;
#pragma unroll
  for (int kc = 0; kc < NKC; ++kc) {
    const int off = ((aoff + kc * 32 + ko) * 2) ^ rx;
    bf16x8 ah0 = *(const bf16x8*)(pAh0 + off);
    bf16x8 ah1 = *(const bf16x8*)(pAh1 + off);
    bf16x8 al0 = *(const bf16x8*)(pAl0 + off);
    bf16x8 al1 = *(const bf16x8*)(pAl1 + off);
    acc0 = MFMA16(ah0, bhp[kc], acc0, 0, 0, 0);
    acc1 = MFMA16(ah1, bhp[kc], acc1, 0, 0, 0);
    acc0 = MFMA16(ah0, blp[kc], acc0, 0, 0, 0);
    acc1 = MFMA16(ah1, blp[kc], acc1, 0, 0, 0);
    acc0 = MFMA16(al0, bhp[kc], acc0, 0, 0, 0);
    acc1 = MFMA16(al1, bhp[kc], acc1, 0, 0, 0);
  }
}

__device__ __forceinline__ void finq(float* glf, int g, int lane,
                                     const f32x4& a0, const f32x4& a1) {
  // C/D layout: col = lane&15, row = (lane>>4)*4 + reg  [measured m89]
  const int col = lane & 15;
  const int r0  = (lane >> 4) * 4;
  float* base = glf + g * 512;
#pragma unroll
  for (int r = 0; r < 4; ++r) {
    atomicAdd(base + (r0 + r) * 16 + col, a0[r]);        // ds_add_f32
    atomicAdd(base + (16 + r0 + r) * 16 + col, a1[r]);
  }
}

// update (tid<512): read 4 gates, zero them, LSTM cell, pack h -> LDS hbuf.
__device__ __forceinline__ void do_update(float* glf, float& c, const float* bs,
                                          int tid, unsigned (*hbuf)[16]) {
  float gi = glf[tid]        + bs[0];
  float gf = glf[512 + tid]  + bs[1];
  float gg = glf[1024 + tid] + bs[2];
  float go = glf[1536 + tid] + bs[3];
  glf[tid] = 0.f; glf[512 + tid] = 0.f; glf[1024 + tid] = 0.f; glf[1536 + tid] = 0.f;
  float i = sigm(gi), f = sigm(gf), g = tanh_f(gg), o = sigm(go);
  float cc = f * c + i * g;
  c = cc;
  float h = o * tanh_f(cc);
  unsigned short hh = f2bf(h);
  unsigned short hl = f2bf(h - bf2f(hh));
  hbuf[tid >> 4][tid & 15] = (unsigned)hh | ((unsigned)hl << 16);
}

// store phase: 128 threads write the 32x16 packed h tile as 2x u64 coherent stores.
__device__ __forceinline__ void store_h(const unsigned (*hbuf)[16], unsigned* hc,
                                        int b0, int hid0, int tid) {
  if (tid < 128) {
    const int row = tid >> 2, q = tid & 3;
    const unsigned long long* src = (const unsigned long long*)&hbuf[row][q * 4];
    unsigned long long* dst =
        (unsigned long long*)(hc + (size_t)(b0 + row) * HID + hid0 + q * 4);
    __hip_atomic_store(dst, src[0], __ATOMIC_RELAXED, __HIP_MEMORY_SCOPE_AGENT);
    __hip_atomic_store(dst + 1, src[1], __ATOMIC_RELAXED, __HIP_MEMORY_SCOPE_AGENT);
  }
}

// Per-group 32-WG barrier: drain vmem, syncthreads, tid0 counter round-trip.
__device__ __forceinline__ void group_barrier(unsigned* cnt, unsigned target, int tid) {
  asm volatile("s_waitcnt vmcnt(0)" ::: "memory");
  __syncthreads();
  if (tid == 0) {
    __hip_atomic_fetch_add(cnt, 1u, __ATOMIC_RELAXED, __HIP_MEMORY_SCOPE_AGENT);
    while (__hip_atomic_load(cnt, __ATOMIC_RELAXED, __HIP_MEMORY_SCOPE_AGENT) < target)
      __builtin_amdgcn_s_sleep(1);
  }
  __syncthreads();
}

// ---------------------------------------------------------------------------
// Persistent fused 2-layer LSTM. 256 WGs x 1024 thr (16 waves, 4/SIMD).
// Wave w: gate g = w&3, K-quarter kq = w>>2; gate partials via LDS atomicAdd.
// slice = blk&31 (16 hidden cols), grp = blk>>5 (32 batch rows).
// h exchanged as packed (hi|lo<<16) dwords via wide device-coherent accesses.
// ---------------------------------------------------------------------------
__global__ void __launch_bounds__(1024, 4) lstm_fused(
    const float* __restrict__ x,
    const float* __restrict__ Wfc, const float* __restrict__ bfc,
    const short* __restrict__ W0h, const short* __restrict__ W0l,
    const short* __restrict__ W1h, const short* __restrict__ W1l,
    const float* __restrict__ bsum0, const float* __restrict__ bsum1,
    unsigned* __restrict__ h0s, unsigned* __restrict__ h2s,
    unsigned* __restrict__ counters,
    float* __restrict__ out) {
  const int tid   = threadIdx.x;
  const int wv    = tid >> 6;
  const int lane  = tid & 63;
  const int slice = blockIdx.x & 31;
  const int grp   = blockIdx.x >> 5;
  const int hid0  = slice * 16;
  const int b0    = grp * 32;
  unsigned* cnt   = counters + grp * 64;

  __shared__ __align__(16) char AhiB[32 * ROWB];      // 73728 B
  __shared__ __align__(16) char AloB[32 * ROWB];      // 73728 B
  __shared__ float glf[4 * 512];                       // 8192 B (also FC scratch)
  __shared__ __align__(16) unsigned hbuf[32][16];      // 2048 B packed-h repack

  const int g  = wv & 3;
  const int kq = wv >> 2;
  const short* B0hp = W0h + ((size_t)(slice * 4 + g) * NC0 + (size_t)kq * 5) * 512;
  const short* B0lp = W0l + ((size_t)(slice * 4 + g) * NC0 + (size_t)kq * 5) * 512;
  const short* B1hp = W1h + ((size_t)(slice * 4 + g) * NC1 + (size_t)kq * 8) * 512;
  const short* B1lp = W1l + ((size_t)(slice * 4 + g) * NC1 + (size_t)kq * 8) * 512;
  const int aoff0 = kq * 160;
  const int aoff1 = IN_DIM + kq * 256;

  float c0 = 0.f, c1 = 0.f;
  float bs0[4], bs1[4];
  if (tid < 512) {
    const int n = hid0 + (tid & 15);
#pragma unroll
    for (int q = 0; q < 4; ++q) { bs0[q] = bsum0[q * HID + n]; bs1[q] = bsum1[q * HID + n]; }
    glf[tid] = 0.f; glf[512 + tid] = 0.f; glf[1024 + tid] = 0.f; glf[1536 + tid] = 0.f;
  }

  const size_t PL = (size_t)BATCH * HID;

  for (int s = 0; s <= SEQT; ++s) {
    const int cur = s & 1, prv = cur ^ 1;
    unsigned* h0c = h0s + (size_t)cur * PL;
    const unsigned* h0p = h0s + (size_t)prv * PL;
    unsigned* h2c = h2s + (size_t)cur * PL;
    const unsigned* h2p = h2s + (size_t)prv * PL;

    // ---- stage phase ----
    if (s < SEQT) {  // x_t -> cols [0,128) hi/lo (plain cached loads)
      const int row = tid >> 5, t32 = tid & 31;
      const int rx = (row & 7) << 4;
      const float* xs = x + ((size_t)(b0 + row) * SEQT + s) * IN_DIM + t32 * 4;
      float4 xv = *(const float4*)xs;
      unsigned short h0v = f2bf(xv.x), h1v = f2bf(xv.y), h2v = f2bf(xv.z), h3v = f2bf(xv.w);
      uint2 hd = {(unsigned)h0v | ((unsigned)h1v << 16), (unsigned)h2v | ((unsigned)h3v << 16)};
      uint2 ld = {(unsigned)f2bf(xv.x - bf2f(h0v)) | ((unsigned)f2bf(xv.y - bf2f(h1v)) << 16),
                  (unsigned)f2bf(xv.z - bf2f(h2v)) | ((unsigned)f2bf(xv.w - bf2f(h3v)) << 16)};
      const int byte = (t32 * 8) ^ rx;
      *(uint2*)(AhiB + row * ROWB + byte) = hd;
      *(uint2*)(AloB + row * ROWB + byte) = ld;
    }
    stage_both(AhiB, AloB, h0p, h2p, b0, tid);   // h2p region garbage at s=0 (unused)
    __syncthreads();

    // ---- layer 0 (t = s) ----
    if (s < SEQT) {
      f32x4 a0 = {0.f, 0.f, 0.f, 0.f}, a1 = {0.f, 0.f, 0.f, 0.f};
      gemmq<3>(AhiB, AloB, B0hp, B0lp, lane, aoff0, a0, a1);
      gemmq<2>(AhiB, AloB, B0hp + 3 * 512, B0lp + 3 * 512, lane, aoff0 + 96, a0, a1);
      finq(glf, g, lane, a0, a1);
    }
    __syncthreads();
    if (s < SEQT && tid < 512) do_update(glf, c0, bs0, tid, hbuf);
    __syncthreads();   // hbuf + gl zeros visible

    // ---- store h0, overlapped with layer 1 (t = s-1) ----
    if (s < SEQT) store_h(hbuf, h0c, b0, hid0, tid);
    if (s > 0) {
      f32x4 a0 = {0.f, 0.f, 0.f, 0.f}, a1 = {0.f, 0.f, 0.f, 0.f};
      gemmq<4>(AhiB, AloB, B1hp, B1lp, lane, aoff1, a0, a1);
      gemmq<4>(AhiB, AloB, B1hp + 4 * 512, B1lp + 4 * 512, lane, aoff1 + 128, a0, a1);
      finq(glf, g, lane, a0, a1);
    }
    __syncthreads();
    if (s > 0 && tid < 512) do_update(glf, c1, bs1, tid, hbuf);
    __syncthreads();   // hbuf visible
    if (s > 0) store_h(hbuf, h2c, b0, hid0, tid);

    group_barrier(cnt, 32u * (unsigned)(s + 1), tid);
  }

  // ---- FC epilogue: slice-0 WG of each group (h2 final in buf 0) ----
  {
    const int p = tid >> 3, q = tid & 7;   // 64 (row,out) pairs x 8 K-eighths
    float acc = 0.f;
    if (slice == 0 && tid < 512) {
      const int b = b0 + (p >> 1), o = p & 1;
      const unsigned* sp = h2s + (size_t)b * HID + q * 64;
      const float* wf = Wfc + (size_t)o * HID + q * 64;
#pragma unroll 8
      for (int i = 0; i < 64; ++i) {
        unsigned u = ald(sp + i);
        acc += (bf2f((unsigned short)(u & 0xffff)) + bf2f((unsigned short)(u >> 16))) * wf[i];
      }
      glf[p * 8 + q] = acc;
    }
    __syncthreads();
    if (slice == 0 && tid < 512 && q == 0) {
      float t = 0.f;
#pragma unroll
      for (int i = 0; i < 8; ++i) t += glf[p * 8 + i];
      out[(b0 + (p >> 1)) * 2 + (p & 1)] = t + bfc[p & 1];
    }
  }
}

// ---------------------------------------------------------------------------
extern "C" void kernel_launch(void* const* d_in, const int* in_sizes, int n_in,
                              void* d_out, int out_size, void* d_ws, size_t ws_size,
                              hipStream_t stream) {
  const float* x    = (const float*)d_in[0];
  const float* Wih0 = (const float*)d_in[1];
  const float* Whh0 = (const float*)d_in[2];
  const float* bih0 = (const float*)d_in[3];
  const float* bhh0 = (const float*)d_in[4];
  const float* Wih1 = (const float*)d_in[5];
  const float* Whh1 = (const float*)d_in[6];
  const float* bih1 = (const float*)d_in[7];
  const float* bhh1 = (const float*)d_in[8];
  const float* Wfc  = (const float*)d_in[9];
  const float* bfc  = (const float*)d_in[10];
  float* out = (float*)d_out;

  // Workspace layout (~15.7 MB)
  short* W0h = (short*)d_ws;
  short* W0l = W0h + (size_t)G4H * K0;
  short* W1h = W0l + (size_t)G4H * K0;
  short* W1l = W1h + (size_t)G4H * K1;
  unsigned* h0s = (unsigned*)(W1l + (size_t)G4H * K1);   // [2 buf][BATCH][HID] packed
  unsigned* h2s = h0s + (size_t)2 * BATCH * HID;
  unsigned* counters = h2s + (size_t)2 * BATCH * HID;     // 8 x 64 dw
  float* bsum0 = (float*)(counters + 512);
  float* bsum1 = bsum0 + G4H;

  // Zero h double-buffers + counters (every launch: graph-replay safe)
  (void)hipMemsetAsync(h0s, 0,
                       (size_t)4 * BATCH * HID * sizeof(unsigned) + 512 * sizeof(unsigned),
                       stream);

  const int total = G4H * K0 + G4H * K1 + 2 * G4H;
  conv_weights<<<(total + 255) / 256, 256, 0, stream>>>(
      Wih0, Whh0, Wih1, Whh1, bih0, bhh0, bih1, bhh1,
      W0h, W0l, W1h, W1l, bsum0, bsum1);

  void* args[] = {(void*)&x,    (void*)&Wfc,  (void*)&bfc,
                  (void*)&W0h,  (void*)&W0l,  (void*)&W1h, (void*)&W1l,
                  (void*)&bsum0, (void*)&bsum1,
                  (void*)&h0s,  (void*)&h2s,  (void*)&counters, (void*)&out};
  (void)hipLaunchCooperativeKernel((void*)lstm_fused, dim3(256), dim3(1024), args, 0,
                                   stream);
}